// Round 1
// baseline (10340.902 us; speedup 1.0000x reference)
//
#include <hip/hip_runtime.h>
#include <cstdint>
#include <math.h>

#define NBATCH 4
#define HH 50
#define WW 76
#define HWPIX 3800
#define HPAD 3840
#define NPROP 34200     // 50*76*9
#define NSORT 65536
#define PRE 6000
#define POST 300

// py-faster-rcnn anchors, base 16, ratios {0.5,1,2}, scales {8,16,32} (exact integers)
__device__ __constant__ double d_AB[9][4] = {
  {-84.0,-40.0,99.0,55.0},
  {-176.0,-88.0,191.0,103.0},
  {-360.0,-184.0,375.0,199.0},
  {-56.0,-56.0,71.0,71.0},
  {-120.0,-120.0,135.0,135.0},
  {-248.0,-248.0,263.0,263.0},
  {-36.0,-80.0,51.0,95.0},
  {-80.0,-168.0,95.0,183.0},
  {-168.0,-344.0,183.0,359.0}
};

// ---------------- 1) transpose conv weights [512][9216] -> [9216][512] -----------
__global__ void transpose_w(const float* __restrict__ src, float* __restrict__ dst){
  __shared__ float t[32][33];
  const int kb = blockIdx.x*32, ob = blockIdx.y*32;
  const int lx = threadIdx.x, ly = threadIdx.y;   // 32 x 8
  #pragma unroll
  for (int m = 0; m < 32; m += 8){
    t[ly+m][lx] = src[(size_t)(ob+ly+m)*9216 + kb + lx];
  }
  __syncthreads();
  #pragma unroll
  for (int m = 0; m < 32; m += 8){
    dst[(size_t)(kb+ly+m)*512 + ob + lx] = t[lx][ly+m];
  }
}

// ---------------- 2) pack head weights into [c][64] (18 cls + 36 bbox + pad) -----
__global__ void prep_head_w(const float* __restrict__ cls_w, const float* __restrict__ bbox_w,
                            float* __restrict__ wh){
  int g = blockIdx.x*256 + threadIdx.x;
  if (g >= 512*64) return;
  int c = g >> 6, o = g & 63;
  float v = 0.0f;
  if (o < 18) v = cls_w[o*512 + c];
  else if (o < 54) v = bbox_w[(o-18)*512 + c];
  wh[g] = v;
}

// ---------------- 3) 3x3 conv + bias + relu, f64 accumulate, f32 out -------------
// block: 320 thr = 16 oc-groups x 20 pix-groups; tile = 64 oc x (10 rows x 16 cols)
__global__ __launch_bounds__(320, 3) void conv3x3(
    const float* __restrict__ in, const float* __restrict__ wt,
    const float* __restrict__ bias, float* __restrict__ xout)
{
  __shared__ __align__(16) double wT[8*9*64];     // [(ic*9+tap)*64 + oc]
  __shared__ __align__(16) double inT[8*12*20];   // [ic*240 + ry*20 + rx], rx<18 used
  const int tid = threadIdx.x;
  const int og = tid & 15;       // oc group (4 oc)
  const int pg = tid >> 4;       // 0..19
  const int r  = pg >> 1;        // row 0..9
  const int cg = pg & 1;         // col half (8 cols)
  const int tY = blockIdx.x / 5;
  const int tX = blockIdx.x - tY*5;
  const int y0 = tY*10, x0 = tX*16;
  const int ocb = blockIdx.y*64;
  const int b = blockIdx.z;
  const float* inb = in + (size_t)b*1024*HWPIX;

  double acc[4][8];
  #pragma unroll
  for (int a=0;a<4;++a){
    #pragma unroll
    for (int j=0;j<8;++j) acc[a][j]=0.0;
  }

  #pragma unroll 1
  for (int icb = 0; icb < 1024; icb += 8){
    for (int m = tid; m < 4608; m += 320){
      int row = m >> 6; int oc = m & 63;
      wT[m] = (double)wt[(size_t)(icb*9 + row)*512 + ocb + oc];
    }
    for (int m = tid; m < 1728; m += 320){
      int ic = m / 216; int rem = m - ic*216;
      int ry = rem / 18; int rx = rem - ry*18;
      int y = y0 - 1 + ry; int x = x0 - 1 + rx;
      float v = 0.0f;
      if ((unsigned)y < (unsigned)HH && (unsigned)x < (unsigned)WW)
        v = inb[(size_t)(icb+ic)*HWPIX + y*WW + x];
      inT[ic*240 + ry*20 + rx] = (double)v;
    }
    __syncthreads();
    #pragma unroll 1
    for (int ic = 0; ic < 8; ++ic){
      #pragma unroll
      for (int ky = 0; ky < 3; ++ky){
        double win[10];
        const double* ip = &inT[ic*240 + (r+ky)*20 + cg*8];
        #pragma unroll
        for (int w = 0; w < 10; ++w) win[w] = ip[w];
        #pragma unroll
        for (int dx = 0; dx < 3; ++dx){
          const double* wp = &wT[(ic*9 + ky*3 + dx)*64 + og*4];
          double w0 = wp[0], w1 = wp[1], w2 = wp[2], w3 = wp[3];
          #pragma unroll
          for (int j = 0; j < 8; ++j){
            double iv = win[j+dx];
            acc[0][j] = fma(iv, w0, acc[0][j]);
            acc[1][j] = fma(iv, w1, acc[1][j]);
            acc[2][j] = fma(iv, w2, acc[2][j]);
            acc[3][j] = fma(iv, w3, acc[3][j]);
          }
        }
      }
    }
    __syncthreads();
  }
  const int yy = y0 + r;
  const int colbase = x0 + cg*8;
  #pragma unroll
  for (int oo = 0; oo < 4; ++oo){
    const int oc = ocb + og*4 + oo;
    const double bo = (double)bias[oc];
    float vals[8];
    #pragma unroll
    for (int j = 0; j < 8; ++j) vals[j] = (float)fmax(acc[oo][j] + bo, 0.0);
    float* op = xout + ((size_t)b*512 + oc)*HWPIX + yy*WW + colbase;
    *(float4*)op = make_float4(vals[0],vals[1],vals[2],vals[3]);
    if (colbase + 7 < WW)
      *(float4*)(op+4) = make_float4(vals[4],vals[5],vals[6],vals[7]);
  }
}

// ---------------- 4) 1x1 heads: hout[b][o<64][p<3840] = sum_c x[b][c][p]*wh[c][o]
__global__ __launch_bounds__(256) void head_mm(const float* __restrict__ x,
    const float* __restrict__ wh, double* __restrict__ hout)
{
  __shared__ float xs[32*128];
  __shared__ float wls[32*64];
  const int tid = threadIdx.x;
  const int b = blockIdx.y;
  const int p0 = blockIdx.x*128;
  const int oct = tid >> 5;      // 8 o-octets
  const int pq = tid & 31;       // 32 pixel quads
  double acc[8][4];
  #pragma unroll
  for (int k=0;k<8;++k){
    #pragma unroll
    for (int j=0;j<4;++j) acc[k][j]=0.0;
  }
  const float* xb = x + (size_t)b*512*HWPIX;
  #pragma unroll 1
  for (int cb = 0; cb < 512; cb += 32){
    for (int m = tid; m < 4096; m += 256){
      int cc = m >> 7; int px = m & 127;
      int p = p0 + px;
      xs[m] = (p < HWPIX) ? xb[(size_t)(cb+cc)*HWPIX + p] : 0.0f;
    }
    for (int m = tid; m < 2048; m += 256)
      wls[m] = wh[(size_t)(cb + (m >> 6))*64 + (m & 63)];
    __syncthreads();
    #pragma unroll 1
    for (int cc = 0; cc < 32; ++cc){
      const float4 xv = *(const float4*)&xs[cc*128 + pq*4];
      double xd0 = (double)xv.x, xd1 = (double)xv.y, xd2 = (double)xv.z, xd3 = (double)xv.w;
      const float* wp = &wls[cc*64 + oct*8];
      #pragma unroll
      for (int k = 0; k < 8; ++k){
        double w = (double)wp[k];
        acc[k][0] = fma(w, xd0, acc[k][0]);
        acc[k][1] = fma(w, xd1, acc[k][1]);
        acc[k][2] = fma(w, xd2, acc[k][2]);
        acc[k][3] = fma(w, xd3, acc[k][3]);
      }
    }
    __syncthreads();
  }
  #pragma unroll
  for (int k = 0; k < 8; ++k){
    #pragma unroll
    for (int j = 0; j < 4; ++j)
      hout[((size_t)b*64 + oct*8 + k)*HPAD + p0 + pq*4 + j] = acc[k][j];
  }
}

// ---------------- 5) sigmoid + anchor decode + clip + min-size + sort keys -------
__global__ void decode_boxes(const double* __restrict__ hout, const float* __restrict__ im_info,
    const float* __restrict__ cls_b, const float* __restrict__ bbox_b,
    double* __restrict__ sc, double* __restrict__ bxs, ulonglong2* __restrict__ keys)
{
  int g = blockIdx.x*256 + threadIdx.x;
  int b = g >> 16;
  int n = g & 65535;
  if (b >= NBATCH) return;
  ulonglong2 kv;
  if (n < NPROP){
    int p = n / 9; int a = n - p*9;
    int yr = p / WW; int xc = p - yr*WW;
    const double* hb = hout + (size_t)b*64*HPAD;
    double l0 = hb[(size_t)a*HPAD + p] + (double)cls_b[a];
    double l1 = hb[(size_t)(9+a)*HPAD + p] + (double)cls_b[9+a];
    double score = 1.0/(1.0 + exp(l0 - l1));
    double d0 = hb[(size_t)(18+4*a+0)*HPAD+p] + (double)bbox_b[4*a+0];
    double d1 = hb[(size_t)(18+4*a+1)*HPAD+p] + (double)bbox_b[4*a+1];
    double d2 = hb[(size_t)(18+4*a+2)*HPAD+p] + (double)bbox_b[4*a+2];
    double d3 = hb[(size_t)(18+4*a+3)*HPAD+p] + (double)bbox_b[4*a+3];
    double sx = 16.0*xc, sy = 16.0*yr;
    double ax1 = d_AB[a][0]+sx, ay1 = d_AB[a][1]+sy;
    double ax2 = d_AB[a][2]+sx, ay2 = d_AB[a][3]+sy;
    double aw = ax2-ax1+1.0, ah = ay2-ay1+1.0;
    double axc = ax1+0.5*aw, ayc = ay1+0.5*ah;
    double cx = axc + d0*aw, cy = ayc + d1*ah;
    double pw = exp(d2)*aw, ph = exp(d3)*ah;
    double i0 = (double)im_info[b*3+0];
    double i1 = (double)im_info[b*3+1];
    double i2 = (double)im_info[b*3+2];
    double x1 = cx - 0.5*pw, y1 = cy - 0.5*ph;
    double x2 = cx + 0.5*pw, y2 = cy + 0.5*ph;
    x1 = fmin(fmax(x1, 0.0), i1-1.0);
    x2 = fmin(fmax(x2, 0.0), i1-1.0);
    y1 = fmin(fmax(y1, 0.0), i0-1.0);
    y2 = fmin(fmax(y2, 0.0), i0-1.0);
    double wsz = x2-x1+1.0, hsz = y2-y1+1.0;
    double ms = 16.0*i2;
    double s = (wsz >= ms && hsz >= ms) ? score : -INFINITY;
    sc[(size_t)b*NPROP + n] = s;
    double* bp = bxs + ((size_t)b*NPROP + n)*4;
    bp[0]=x1; bp[1]=y1; bp[2]=x2; bp[3]=y2;
    // monotone-descending 64-bit key with ascending-index tiebreak (top_k stability)
    unsigned long long u = (unsigned long long)__double_as_longlong(s);
    unsigned long long mm = (u >> 63) ? ~u : (u | 0x8000000000000000ULL);
    kv.x = ~mm; kv.y = (unsigned long long)n;
  } else {
    kv.x = ~0ULL; kv.y = (unsigned long long)n;   // padding sorts last
  }
  keys[(size_t)b*NSORT + n] = kv;
}

// ---------------- 6) bitonic sort of 65536 (key,idx), one block per image --------
__device__ __forceinline__ bool kgt(const ulonglong2& a, const ulonglong2& b){
  return (a.x > b.x) || (a.x == b.x && a.y > b.y);
}
__global__ __launch_bounds__(1024) void bitonic_sort(ulonglong2* __restrict__ keys){
  const int b = blockIdx.x;
  ulonglong2* base = keys + (size_t)b*NSORT;
  __shared__ ulonglong2 L[2048];
  const int tid = threadIdx.x;
  // phase 1: all stages k<=2048, per 2048-chunk in LDS
  for (int c = 0; c < 32; ++c){
    L[tid]      = base[c*2048 + tid];
    L[tid+1024] = base[c*2048 + tid + 1024];
    __syncthreads();
    for (int k = 2; k <= 2048; k <<= 1){
      for (int j = k>>1; j > 0; j >>= 1){
        int i = ((tid & ~(j-1)) << 1) | (tid & (j-1));
        int l = i | j;
        bool asc = (((c*2048 + i) & k) == 0);
        ulonglong2 A = L[i], Bv = L[l];
        if (kgt(A,Bv) == asc){ L[i] = Bv; L[l] = A; }
        __syncthreads();
      }
    }
    base[c*2048+tid]      = L[tid];
    base[c*2048+tid+1024] = L[tid+1024];
    __threadfence();
    __syncthreads();
  }
  // phase 2: stages k = 4096 .. 65536
  for (int k = 4096; k <= 65536; k <<= 1){
    for (int j = k>>1; j >= 2048; j >>= 1){
      for (int m = 0; m < 32; ++m){
        int q = m*1024 + tid;
        int i = ((q & ~(j-1)) << 1) | (q & (j-1));
        int l = i | j;
        bool asc = ((i & k) == 0);
        ulonglong2 A = base[i], Bv = base[l];
        if (kgt(A,Bv) == asc){ base[i] = Bv; base[l] = A; }
      }
      __threadfence();
      __syncthreads();
    }
    for (int c = 0; c < 32; ++c){
      L[tid]      = base[c*2048+tid];
      L[tid+1024] = base[c*2048+tid+1024];
      __syncthreads();
      for (int j = 1024; j > 0; j >>= 1){
        int i = ((tid & ~(j-1)) << 1) | (tid & (j-1));
        int l = i | j;
        bool asc = (((c*2048 + i) & k) == 0);
        ulonglong2 A = L[i], Bv = L[l];
        if (kgt(A,Bv) == asc){ L[i] = Bv; L[l] = A; }
        __syncthreads();
      }
      base[c*2048+tid]      = L[tid];
      base[c*2048+tid+1024] = L[tid+1024];
      __threadfence();
      __syncthreads();
    }
  }
}

// ---------------- 7) gather top-6000 ---------------------------------------------
__global__ void gather_top(const ulonglong2* __restrict__ keys, const double* __restrict__ sc,
    const double* __restrict__ bxs, double* __restrict__ tsc, double* __restrict__ tbx)
{
  int r = blockIdx.x*256 + threadIdx.x;
  int b = blockIdx.y;
  if (r >= PRE) return;
  int idx = (int)keys[(size_t)b*NSORT + r].y;
  tsc[(size_t)b*PRE + r] = sc[(size_t)b*NPROP + idx];
  const double* sp = bxs + ((size_t)b*NPROP + idx)*4;
  double* dp = tbx + ((size_t)b*PRE + r)*4;
  dp[0]=sp[0]; dp[1]=sp[1]; dp[2]=sp[2]; dp[3]=sp[3];
}

// ---------------- 8) greedy NMS (exact argmax-loop semantics), 1 block/image -----
__global__ __launch_bounds__(1024) void nms_kernel(const double* __restrict__ tsc,
    const double* __restrict__ tbx, float* __restrict__ out)
{
  const int b = blockIdx.x;
  const int tid = threadIdx.x;
  __shared__ double sm[PRE];
  __shared__ double rv[16];
  __shared__ int ri[16];
  __shared__ double bb[5];
  const double* scb = tsc + (size_t)b*PRE;
  const double* bkb = tbx + (size_t)b*PRE*4;
  double bx[6][4];   // this thread's boxes live in registers
  #pragma unroll
  for (int t = 0; t < 6; ++t){
    int i = t*1024 + tid;
    if (i < PRE){
      sm[i] = scb[i];
      bx[t][0] = bkb[i*4+0];
      bx[t][1] = bkb[i*4+1];
      bx[t][2] = bkb[i*4+2];
      bx[t][3] = bkb[i*4+3];
    }
  }
  __syncthreads();
  for (int it = 0; it < POST; ++it){
    double bv = -INFINITY; int bi = 0x7FFFFFFF;
    #pragma unroll
    for (int t = 0; t < 6; ++t){
      int i = t*1024 + tid;
      if (i < PRE){
        double v = sm[i];
        if (v > bv || (v == bv && i < bi)){ bv = v; bi = i; }
      }
    }
    #pragma unroll
    for (int off = 32; off > 0; off >>= 1){
      double ov = __shfl_down(bv, off);
      int oi = __shfl_down(bi, off);
      if (ov > bv || (ov == bv && oi < bi)){ bv = ov; bi = oi; }
    }
    if ((tid & 63) == 0){ rv[tid>>6] = bv; ri[tid>>6] = bi; }
    __syncthreads();
    if (tid == 0){
      for (int w = 1; w < 16; ++w){
        if (rv[w] > bv || (rv[w] == bv && ri[w] < bi)){ bv = rv[w]; bi = ri[w]; }
      }
      double jx1 = bkb[bi*4+0], jy1 = bkb[bi*4+1], jx2 = bkb[bi*4+2], jy2 = bkb[bi*4+3];
      bb[0]=jx1; bb[1]=jy1; bb[2]=jx2; bb[3]=jy2;
      bb[4] = (jx2-jx1+1.0)*(jy2-jy1+1.0);
      out[b*POST + it] = (float)scb[bi];
      float* ob = out + NBATCH*POST + (size_t)(b*POST + it)*4;
      ob[0]=(float)jx1; ob[1]=(float)jy1; ob[2]=(float)jx2; ob[3]=(float)jy2;
    }
    __syncthreads();
    double jx1 = bb[0], jy1 = bb[1], jx2 = bb[2], jy2 = bb[3], ja = bb[4];
    #pragma unroll
    for (int t = 0; t < 6; ++t){
      int i = t*1024 + tid;
      if (i < PRE){
        double xx1 = fmax(jx1, bx[t][0]);
        double yy1 = fmax(jy1, bx[t][1]);
        double xx2 = fmin(jx2, bx[t][2]);
        double yy2 = fmin(jy2, bx[t][3]);
        double iw = fmax(0.0, xx2-xx1+1.0);
        double ih = fmax(0.0, yy2-yy1+1.0);
        double inter = iw*ih;
        double ai = (bx[t][2]-bx[t][0]+1.0)*(bx[t][3]-bx[t][1]+1.0);
        double iou = inter/(ja + ai - inter);
        if (iou > 0.7) sm[i] = -INFINITY;
      }
    }
    __syncthreads();
  }
}

// =================================================================================
extern "C" void kernel_launch(void* const* d_in, const int* in_sizes, int n_in,
                              void* d_out, int out_size, void* d_ws, size_t ws_size,
                              hipStream_t stream) {
  (void)in_sizes; (void)n_in; (void)out_size; (void)ws_size;
  const float* base_feat = (const float*)d_in[0];
  const float* im_info   = (const float*)d_in[1];
  // d_in[2]=gt_boxes, d_in[3]=num_boxes : unused by the reference
  const float* conv_w = (const float*)d_in[4];
  const float* conv_b = (const float*)d_in[5];
  const float* cls_w  = (const float*)d_in[6];
  const float* cls_b  = (const float*)d_in[7];
  const float* bbox_w = (const float*)d_in[8];
  const float* bbox_b = (const float*)d_in[9];
  float* out = (float*)d_out;
  char* ws = (char*)d_ws;

  // workspace layout (all offsets 16B-aligned); total ~68.6 MB
  float*      w_t  = (float*)     (ws + 0);           // 9216*512 f32         = 18,874,368 B
  float*      xbuf = (float*)     (ws + 18874368);    // 4*512*3800 f32       = 31,129,600 B
  float*      wh   = (float*)     (ws + 50003968);    // 512*64 f32           =    131,072 B
  double*     hout = (double*)    (ws + 50135040);    // 4*64*3840 f64        =  7,864,320 B
  double*     scb  = (double*)    (ws + 57999360);    // 4*34200 f64          =  1,094,400 B
  double*     bxb  = (double*)    (ws + 59093760);    // 4*34200*4 f64        =  4,377,600 B
  ulonglong2* keys = (ulonglong2*)(ws + 63471360);    // 4*65536*16B          =  4,194,304 B
  double*     tops = (double*)    (ws + 67665664);    // 4*6000 f64           =    192,000 B
  double*     topb = (double*)    (ws + 67857664);    // 4*6000*4 f64         =    768,000 B

  transpose_w <<<dim3(288,16), dim3(32,8), 0, stream>>>(conv_w, w_t);
  prep_head_w <<<128, 256, 0, stream>>>(cls_w, bbox_w, wh);
  conv3x3     <<<dim3(25,8,4), 320, 0, stream>>>(base_feat, w_t, conv_b, xbuf);
  head_mm     <<<dim3(30,4), 256, 0, stream>>>(xbuf, wh, hout);
  decode_boxes<<<1024, 256, 0, stream>>>(hout, im_info, cls_b, bbox_b, scb, bxb, keys);
  bitonic_sort<<<4, 1024, 0, stream>>>(keys);
  gather_top  <<<dim3(24,4), 256, 0, stream>>>(keys, scb, bxb, tops, topb);
  nms_kernel  <<<4, 1024, 0, stream>>>(tops, topb, out);
}

// Round 2
// 7719.352 us; speedup vs baseline: 1.3396x; 1.3396x over previous
//
#include <hip/hip_runtime.h>
#include <cstdint>
#include <math.h>

#define NBATCH 4
#define HH 50
#define WW 76
#define HWPIX 3800
#define HPAD 3840
#define NPROP 34200     // 50*76*9
#define NSORT 65536
#define PRE 6000
#define POST 300

// py-faster-rcnn anchors, base 16, ratios {0.5,1,2}, scales {8,16,32} (exact integers)
__device__ __constant__ double d_AB[9][4] = {
  {-84.0,-40.0,99.0,55.0},
  {-176.0,-88.0,191.0,103.0},
  {-360.0,-184.0,375.0,199.0},
  {-56.0,-56.0,71.0,71.0},
  {-120.0,-120.0,135.0,135.0},
  {-248.0,-248.0,263.0,263.0},
  {-36.0,-80.0,51.0,95.0},
  {-80.0,-168.0,95.0,183.0},
  {-168.0,-344.0,183.0,359.0}
};

// ---------------- 1) transpose conv weights [512][9216] -> [9216][512] -----------
__global__ void transpose_w(const float* __restrict__ src, float* __restrict__ dst){
  __shared__ float t[32][33];
  const int kb = blockIdx.x*32, ob = blockIdx.y*32;
  const int lx = threadIdx.x, ly = threadIdx.y;   // 32 x 8
  #pragma unroll
  for (int m = 0; m < 32; m += 8){
    t[ly+m][lx] = src[(size_t)(ob+ly+m)*9216 + kb + lx];
  }
  __syncthreads();
  #pragma unroll
  for (int m = 0; m < 32; m += 8){
    dst[(size_t)(kb+ly+m)*512 + ob + lx] = t[lx][ly+m];
  }
}

// ---------------- 2) pack head weights into [c][64] (18 cls + 36 bbox + pad) -----
__global__ void prep_head_w(const float* __restrict__ cls_w, const float* __restrict__ bbox_w,
                            float* __restrict__ wh){
  int g = blockIdx.x*256 + threadIdx.x;
  if (g >= 512*64) return;
  int c = g >> 6, o = g & 63;
  float v = 0.0f;
  if (o < 18) v = cls_w[o*512 + c];
  else if (o < 54) v = bbox_w[(o-18)*512 + c];
  wh[g] = v;
}

// ---------------- 3) 3x3 conv + bias + relu, f64 accumulate, f32 out -------------
// block: 320 thr = 16 oc-groups x 20 pix-groups; tile = 64 oc x (10 rows x 16 cols)
// wT pair-plane layout [p][tap][og][2] -> lane stride 16B (2-way alias = free)
// global->reg prefetch pipeline hides HBM latency behind the 8-ic compute chunk
__global__ __launch_bounds__(320, 3) void conv3x3(
    const float* __restrict__ in, const float* __restrict__ wt,
    const float* __restrict__ bias, float* __restrict__ xout)
{
  __shared__ __align__(16) double wT[4608];       // [((p*72+tap)*16+og)*2+j]
  __shared__ __align__(16) double inT[8*12*20];   // [ic*240 + ry*20 + rx], rx<18 used
  const int tid = threadIdx.x;
  const int og = tid & 15;       // oc group (4 oc)
  const int pg = tid >> 4;       // 0..19
  const int r  = pg >> 1;        // row 0..9
  const int cg = pg & 1;         // col half (8 cols)
  const int tY = blockIdx.x / 5;
  const int tX = blockIdx.x - tY*5;
  const int y0 = tY*10, x0 = tX*16;
  const int ocb = blockIdx.y*64;
  const int b = blockIdx.z;
  const float* inb = in + (size_t)b*1024*HWPIX;

  double acc[4][8];
  #pragma unroll
  for (int a=0;a<4;++a){
    #pragma unroll
    for (int j=0;j<8;++j) acc[a][j]=0.0;
  }

  float wr[15], ir[6];

  auto load_chunk = [&](int icb){
    #pragma unroll
    for (int s = 0; s < 15; ++s){
      int m = tid + s*320;
      if (m < 4608){
        int row = m >> 6, oc = m & 63;
        wr[s] = wt[(size_t)(icb*9 + row)*512 + ocb + oc];
      }
    }
    #pragma unroll
    for (int s = 0; s < 6; ++s){
      int m = tid + s*320;
      if (m < 1728){
        int ic = m/216; int rem = m - ic*216;
        int ry = rem/18; int rx = rem - ry*18;
        int y = y0 - 1 + ry; int x = x0 - 1 + rx;
        ir[s] = ((unsigned)y < (unsigned)HH && (unsigned)x < (unsigned)WW)
                  ? inb[(size_t)(icb+ic)*HWPIX + y*WW + x] : 0.0f;
      }
    }
  };
  auto store_chunk = [&](){
    #pragma unroll
    for (int s = 0; s < 15; ++s){
      int m = tid + s*320;
      if (m < 4608){
        int row = m >> 6, oc = m & 63;
        int oo = oc & 3, ogw = oc >> 2, p = oo >> 1, jj = oo & 1;
        wT[(((p*72 + row)*16 + ogw) << 1) + jj] = (double)wr[s];
      }
    }
    #pragma unroll
    for (int s = 0; s < 6; ++s){
      int m = tid + s*320;
      if (m < 1728){
        int ic = m/216; int rem = m - ic*216;
        int ry = rem/18; int rx = rem - ry*18;
        inT[ic*240 + ry*20 + rx] = (double)ir[s];
      }
    }
  };

  load_chunk(0);
  store_chunk();
  __syncthreads();

  #pragma unroll 1
  for (int icb = 0; icb < 1024; icb += 8){
    const bool more = (icb + 8) < 1024;
    if (more) load_chunk(icb + 8);
    #pragma unroll 1
    for (int ic = 0; ic < 8; ++ic){
      #pragma unroll
      for (int ky = 0; ky < 3; ++ky){
        double win[10];
        const double* ip = &inT[ic*240 + (r+ky)*20 + cg*8];
        #pragma unroll
        for (int w = 0; w < 10; ++w) win[w] = ip[w];
        const int row = ic*9 + ky*3;
        #pragma unroll
        for (int dx = 0; dx < 3; ++dx){
          const double2 wa = *(const double2*)&wT[((row+dx)*16 + og) << 1];
          const double2 wb = *(const double2*)&wT[(((72 + row+dx)*16) + og) << 1];
          const double w0 = wa.x, w1 = wa.y, w2 = wb.x, w3 = wb.y;
          #pragma unroll
          for (int j = 0; j < 8; ++j){
            double iv = win[j+dx];
            acc[0][j] = fma(iv, w0, acc[0][j]);
            acc[1][j] = fma(iv, w1, acc[1][j]);
            acc[2][j] = fma(iv, w2, acc[2][j]);
            acc[3][j] = fma(iv, w3, acc[3][j]);
          }
        }
      }
    }
    __syncthreads();
    if (more) store_chunk();
    __syncthreads();
  }

  const int yy = y0 + r;
  const int colbase = x0 + cg*8;
  #pragma unroll
  for (int oo = 0; oo < 4; ++oo){
    const int oc = ocb + og*4 + oo;
    const double bo = (double)bias[oc];
    float vals[8];
    #pragma unroll
    for (int j = 0; j < 8; ++j) vals[j] = (float)fmax(acc[oo][j] + bo, 0.0);
    float* op = xout + ((size_t)b*512 + oc)*HWPIX + yy*WW + colbase;
    *(float4*)op = make_float4(vals[0],vals[1],vals[2],vals[3]);
    if (colbase + 7 < WW)
      *(float4*)(op+4) = make_float4(vals[4],vals[5],vals[6],vals[7]);
  }
}

// ---------------- 4) 1x1 heads: hout[b][o<64][p<3840] = sum_c x[b][c][p]*wh[c][o]
__global__ __launch_bounds__(256) void head_mm(const float* __restrict__ x,
    const float* __restrict__ wh, double* __restrict__ hout)
{
  __shared__ float xs[32*128];
  __shared__ float wls[32*64];
  const int tid = threadIdx.x;
  const int b = blockIdx.y;
  const int p0 = blockIdx.x*128;
  const int oct = tid >> 5;      // 8 o-octets
  const int pq = tid & 31;       // 32 pixel quads
  double acc[8][4];
  #pragma unroll
  for (int k=0;k<8;++k){
    #pragma unroll
    for (int j=0;j<4;++j) acc[k][j]=0.0;
  }
  const float* xb = x + (size_t)b*512*HWPIX;
  #pragma unroll 1
  for (int cb = 0; cb < 512; cb += 32){
    for (int m = tid; m < 4096; m += 256){
      int cc = m >> 7; int px = m & 127;
      int p = p0 + px;
      xs[m] = (p < HWPIX) ? xb[(size_t)(cb+cc)*HWPIX + p] : 0.0f;
    }
    for (int m = tid; m < 2048; m += 256)
      wls[m] = wh[(size_t)(cb + (m >> 6))*64 + (m & 63)];
    __syncthreads();
    #pragma unroll 1
    for (int cc = 0; cc < 32; ++cc){
      const float4 xv = *(const float4*)&xs[cc*128 + pq*4];
      double xd0 = (double)xv.x, xd1 = (double)xv.y, xd2 = (double)xv.z, xd3 = (double)xv.w;
      const float* wp = &wls[cc*64 + oct*8];
      #pragma unroll
      for (int k = 0; k < 8; ++k){
        double w = (double)wp[k];
        acc[k][0] = fma(w, xd0, acc[k][0]);
        acc[k][1] = fma(w, xd1, acc[k][1]);
        acc[k][2] = fma(w, xd2, acc[k][2]);
        acc[k][3] = fma(w, xd3, acc[k][3]);
      }
    }
    __syncthreads();
  }
  #pragma unroll
  for (int k = 0; k < 8; ++k){
    #pragma unroll
    for (int j = 0; j < 4; ++j)
      hout[((size_t)b*64 + oct*8 + k)*HPAD + p0 + pq*4 + j] = acc[k][j];
  }
}

// ---------------- 5) sigmoid + anchor decode + clip + min-size + sort keys -------
__global__ void decode_boxes(const double* __restrict__ hout, const float* __restrict__ im_info,
    const float* __restrict__ cls_b, const float* __restrict__ bbox_b,
    double* __restrict__ sc, double* __restrict__ bxs, ulonglong2* __restrict__ keys)
{
  int g = blockIdx.x*256 + threadIdx.x;
  int b = g >> 16;
  int n = g & 65535;
  if (b >= NBATCH) return;
  ulonglong2 kv;
  if (n < NPROP){
    int p = n / 9; int a = n - p*9;
    int yr = p / WW; int xc = p - yr*WW;
    const double* hb = hout + (size_t)b*64*HPAD;
    double l0 = hb[(size_t)a*HPAD + p] + (double)cls_b[a];
    double l1 = hb[(size_t)(9+a)*HPAD + p] + (double)cls_b[9+a];
    double score = 1.0/(1.0 + exp(l0 - l1));
    double d0 = hb[(size_t)(18+4*a+0)*HPAD+p] + (double)bbox_b[4*a+0];
    double d1 = hb[(size_t)(18+4*a+1)*HPAD+p] + (double)bbox_b[4*a+1];
    double d2 = hb[(size_t)(18+4*a+2)*HPAD+p] + (double)bbox_b[4*a+2];
    double d3 = hb[(size_t)(18+4*a+3)*HPAD+p] + (double)bbox_b[4*a+3];
    double sx = 16.0*xc, sy = 16.0*yr;
    double ax1 = d_AB[a][0]+sx, ay1 = d_AB[a][1]+sy;
    double ax2 = d_AB[a][2]+sx, ay2 = d_AB[a][3]+sy;
    double aw = ax2-ax1+1.0, ah = ay2-ay1+1.0;
    double axc = ax1+0.5*aw, ayc = ay1+0.5*ah;
    double cx = axc + d0*aw, cy = ayc + d1*ah;
    double pw = exp(d2)*aw, ph = exp(d3)*ah;
    double i0 = (double)im_info[b*3+0];
    double i1 = (double)im_info[b*3+1];
    double i2 = (double)im_info[b*3+2];
    double x1 = cx - 0.5*pw, y1 = cy - 0.5*ph;
    double x2 = cx + 0.5*pw, y2 = cy + 0.5*ph;
    x1 = fmin(fmax(x1, 0.0), i1-1.0);
    x2 = fmin(fmax(x2, 0.0), i1-1.0);
    y1 = fmin(fmax(y1, 0.0), i0-1.0);
    y2 = fmin(fmax(y2, 0.0), i0-1.0);
    double wsz = x2-x1+1.0, hsz = y2-y1+1.0;
    double ms = 16.0*i2;
    double s = (wsz >= ms && hsz >= ms) ? score : -INFINITY;
    sc[(size_t)b*NPROP + n] = s;
    double* bp = bxs + ((size_t)b*NPROP + n)*4;
    bp[0]=x1; bp[1]=y1; bp[2]=x2; bp[3]=y2;
    unsigned long long u = (unsigned long long)__double_as_longlong(s);
    unsigned long long mm = (u >> 63) ? ~u : (u | 0x8000000000000000ULL);
    kv.x = ~mm; kv.y = (unsigned long long)n;
  } else {
    kv.x = ~0ULL; kv.y = (unsigned long long)n;   // padding sorts last
  }
  keys[(size_t)b*NSORT + n] = kv;
}

// ---------------- 6) bitonic sort, multi-kernel (whole-GPU parallel) -------------
__device__ __forceinline__ bool kgt(const ulonglong2& a, const ulonglong2& b){
  return (a.x > b.x) || (a.x == b.x && a.y > b.y);
}
// 6a: sort each 2048-chunk through stages k=2..2048 (128 blocks)
__global__ __launch_bounds__(1024) void sort_local(ulonglong2* __restrict__ keys){
  const int c = blockIdx.x & 31;
  const int b = blockIdx.x >> 5;
  ulonglong2* base = keys + (size_t)b*NSORT + c*2048;
  __shared__ ulonglong2 L[2048];
  const int tid = threadIdx.x;
  L[tid] = base[tid]; L[tid+1024] = base[tid+1024];
  __syncthreads();
  for (int k = 2; k <= 2048; k <<= 1){
    for (int j = k>>1; j > 0; j >>= 1){
      int i = ((tid & ~(j-1)) << 1) | (tid & (j-1));
      int l = i | j;
      bool asc = (((c*2048 + i) & k) == 0);
      ulonglong2 A = L[i], Bv = L[l];
      if (kgt(A,Bv) == asc){ L[i] = Bv; L[l] = A; }
      __syncthreads();
    }
  }
  base[tid] = L[tid]; base[tid+1024] = L[tid+1024];
}
// 6b: one global compare-swap step (j>=2048), 512 blocks x 256
__global__ void sort_gstep(ulonglong2* __restrict__ keys, int k, int j){
  int gid = blockIdx.x*256 + threadIdx.x;
  int b = gid >> 15;
  int q = gid & 32767;
  ulonglong2* base = keys + (size_t)b*NSORT;
  int i = ((q & ~(j-1)) << 1) | (q & (j-1));
  int l = i | j;
  bool asc = ((i & k) == 0);
  ulonglong2 A = base[i], Bv = base[l];
  if (kgt(A,Bv) == asc){ base[i] = Bv; base[l] = A; }
}
// 6c: finish stage k with chunk-local steps j=1024..1 (128 blocks)
__global__ __launch_bounds__(1024) void sort_lmerge(ulonglong2* __restrict__ keys, int k){
  const int c = blockIdx.x & 31;
  const int b = blockIdx.x >> 5;
  ulonglong2* base = keys + (size_t)b*NSORT + c*2048;
  __shared__ ulonglong2 L[2048];
  const int tid = threadIdx.x;
  L[tid] = base[tid]; L[tid+1024] = base[tid+1024];
  __syncthreads();
  for (int j = 1024; j > 0; j >>= 1){
    int i = ((tid & ~(j-1)) << 1) | (tid & (j-1));
    int l = i | j;
    bool asc = (((c*2048 + i) & k) == 0);
    ulonglong2 A = L[i], Bv = L[l];
    if (kgt(A,Bv) == asc){ L[i] = Bv; L[l] = A; }
    __syncthreads();
  }
  base[tid] = L[tid]; base[tid+1024] = L[tid+1024];
}

// ---------------- 7) gather top-6000 ---------------------------------------------
__global__ void gather_top(const ulonglong2* __restrict__ keys, const double* __restrict__ sc,
    const double* __restrict__ bxs, double* __restrict__ tsc, double* __restrict__ tbx)
{
  int r = blockIdx.x*256 + threadIdx.x;
  int b = blockIdx.y;
  if (r >= PRE) return;
  int idx = (int)keys[(size_t)b*NSORT + r].y;
  tsc[(size_t)b*PRE + r] = sc[(size_t)b*NPROP + idx];
  const double* sp = bxs + ((size_t)b*NPROP + idx)*4;
  double* dp = tbx + ((size_t)b*PRE + r)*4;
  dp[0]=sp[0]; dp[1]=sp[1]; dp[2]=sp[2]; dp[3]=sp[3];
}

// ---------------- 8) greedy NMS (exact argmax-loop semantics), 1 block/image -----
__global__ __launch_bounds__(1024) void nms_kernel(const double* __restrict__ tsc,
    const double* __restrict__ tbx, float* __restrict__ out)
{
  const int b = blockIdx.x;
  const int tid = threadIdx.x;
  __shared__ double sm[PRE];
  __shared__ double rv[16];
  __shared__ int ri[16];
  __shared__ double bb[5];
  const double* scb = tsc + (size_t)b*PRE;
  const double* bkb = tbx + (size_t)b*PRE*4;
  double bx[6][4];
  #pragma unroll
  for (int t = 0; t < 6; ++t){
    int i = t*1024 + tid;
    if (i < PRE){
      sm[i] = scb[i];
      bx[t][0] = bkb[i*4+0];
      bx[t][1] = bkb[i*4+1];
      bx[t][2] = bkb[i*4+2];
      bx[t][3] = bkb[i*4+3];
    }
  }
  __syncthreads();
  for (int it = 0; it < POST; ++it){
    double bv = -INFINITY; int bi = 0x7FFFFFFF;
    #pragma unroll
    for (int t = 0; t < 6; ++t){
      int i = t*1024 + tid;
      if (i < PRE){
        double v = sm[i];
        if (v > bv || (v == bv && i < bi)){ bv = v; bi = i; }
      }
    }
    #pragma unroll
    for (int off = 32; off > 0; off >>= 1){
      double ov = __shfl_down(bv, off);
      int oi = __shfl_down(bi, off);
      if (ov > bv || (ov == bv && oi < bi)){ bv = ov; bi = oi; }
    }
    if ((tid & 63) == 0){ rv[tid>>6] = bv; ri[tid>>6] = bi; }
    __syncthreads();
    if (tid == 0){
      for (int w = 1; w < 16; ++w){
        if (rv[w] > bv || (rv[w] == bv && ri[w] < bi)){ bv = rv[w]; bi = ri[w]; }
      }
      double jx1 = bkb[bi*4+0], jy1 = bkb[bi*4+1], jx2 = bkb[bi*4+2], jy2 = bkb[bi*4+3];
      bb[0]=jx1; bb[1]=jy1; bb[2]=jx2; bb[3]=jy2;
      bb[4] = (jx2-jx1+1.0)*(jy2-jy1+1.0);
      out[b*POST + it] = (float)scb[bi];
      float* ob = out + NBATCH*POST + (size_t)(b*POST + it)*4;
      ob[0]=(float)jx1; ob[1]=(float)jy1; ob[2]=(float)jx2; ob[3]=(float)jy2;
    }
    __syncthreads();
    double jx1 = bb[0], jy1 = bb[1], jx2 = bb[2], jy2 = bb[3], ja = bb[4];
    #pragma unroll
    for (int t = 0; t < 6; ++t){
      int i = t*1024 + tid;
      if (i < PRE){
        double xx1 = fmax(jx1, bx[t][0]);
        double yy1 = fmax(jy1, bx[t][1]);
        double xx2 = fmin(jx2, bx[t][2]);
        double yy2 = fmin(jy2, bx[t][3]);
        double iw = fmax(0.0, xx2-xx1+1.0);
        double ih = fmax(0.0, yy2-yy1+1.0);
        double inter = iw*ih;
        double ai = (bx[t][2]-bx[t][0]+1.0)*(bx[t][3]-bx[t][1]+1.0);
        double iou = inter/(ja + ai - inter);
        if (iou > 0.7) sm[i] = -INFINITY;
      }
    }
    __syncthreads();
  }
}

// =================================================================================
extern "C" void kernel_launch(void* const* d_in, const int* in_sizes, int n_in,
                              void* d_out, int out_size, void* d_ws, size_t ws_size,
                              hipStream_t stream) {
  (void)in_sizes; (void)n_in; (void)out_size; (void)ws_size;
  const float* base_feat = (const float*)d_in[0];
  const float* im_info   = (const float*)d_in[1];
  const float* conv_w = (const float*)d_in[4];
  const float* conv_b = (const float*)d_in[5];
  const float* cls_w  = (const float*)d_in[6];
  const float* cls_b  = (const float*)d_in[7];
  const float* bbox_w = (const float*)d_in[8];
  const float* bbox_b = (const float*)d_in[9];
  float* out = (float*)d_out;
  char* ws = (char*)d_ws;

  float*      w_t  = (float*)     (ws + 0);           // 9216*512 f32
  float*      xbuf = (float*)     (ws + 18874368);    // 4*512*3800 f32
  float*      wh   = (float*)     (ws + 50003968);    // 512*64 f32
  double*     hout = (double*)    (ws + 50135040);    // 4*64*3840 f64
  double*     scb  = (double*)    (ws + 57999360);    // 4*34200 f64
  double*     bxb  = (double*)    (ws + 59093760);    // 4*34200*4 f64
  ulonglong2* keys = (ulonglong2*)(ws + 63471360);    // 4*65536*16B
  double*     tops = (double*)    (ws + 67665664);    // 4*6000 f64
  double*     topb = (double*)    (ws + 67857664);    // 4*6000*4 f64

  transpose_w <<<dim3(288,16), dim3(32,8), 0, stream>>>(conv_w, w_t);
  prep_head_w <<<128, 256, 0, stream>>>(cls_w, bbox_w, wh);
  conv3x3     <<<dim3(25,8,4), 320, 0, stream>>>(base_feat, w_t, conv_b, xbuf);
  head_mm     <<<dim3(30,4), 256, 0, stream>>>(xbuf, wh, hout);
  decode_boxes<<<1024, 256, 0, stream>>>(hout, im_info, cls_b, bbox_b, scb, bxb, keys);

  sort_local  <<<128, 1024, 0, stream>>>(keys);
  for (int k = 4096; k <= 65536; k <<= 1){
    for (int j = k>>1; j >= 2048; j >>= 1)
      sort_gstep<<<512, 256, 0, stream>>>(keys, k, j);
    sort_lmerge<<<128, 1024, 0, stream>>>(keys, k);
  }

  gather_top  <<<dim3(24,4), 256, 0, stream>>>(keys, scb, bxb, tops, topb);
  nms_kernel  <<<4, 1024, 0, stream>>>(tops, topb, out);
}

// Round 4
// 4447.386 us; speedup vs baseline: 2.3252x; 1.7357x over previous
//
#include <hip/hip_runtime.h>
#include <cstdint>
#include <math.h>

#define NBATCH 4
#define HH 50
#define WW 76
#define HWPIX 3800
#define HPAD 3840
#define NPROP 34200     // 50*76*9
#define NSORT 65536
#define PRE 6000
#define POST 300

typedef double double4v __attribute__((ext_vector_type(4)));

// py-faster-rcnn anchors, base 16, ratios {0.5,1,2}, scales {8,16,32} (exact integers)
__device__ __constant__ double d_AB[9][4] = {
  {-84.0,-40.0,99.0,55.0},
  {-176.0,-88.0,191.0,103.0},
  {-360.0,-184.0,375.0,199.0},
  {-56.0,-56.0,71.0,71.0},
  {-120.0,-120.0,135.0,135.0},
  {-248.0,-248.0,263.0,263.0},
  {-36.0,-80.0,51.0,95.0},
  {-80.0,-168.0,95.0,183.0},
  {-168.0,-344.0,183.0,359.0}
};

// ---------------- 1) transpose conv weights [512][9216] -> [9216][512] -----------
__global__ void transpose_w(const float* __restrict__ src, float* __restrict__ dst){
  __shared__ float t[32][33];
  const int kb = blockIdx.x*32, ob = blockIdx.y*32;
  const int lx = threadIdx.x, ly = threadIdx.y;   // 32 x 8
  #pragma unroll
  for (int m = 0; m < 32; m += 8){
    t[ly+m][lx] = src[(size_t)(ob+ly+m)*9216 + kb + lx];
  }
  __syncthreads();
  #pragma unroll
  for (int m = 0; m < 32; m += 8){
    dst[(size_t)(kb+ly+m)*512 + ob + lx] = t[lx][ly+m];
  }
}

// ---------------- 2) pack head weights into [c][64] (18 cls + 36 bbox + pad) -----
__global__ void prep_head_w(const float* __restrict__ cls_w, const float* __restrict__ bbox_w,
                            float* __restrict__ wh){
  int g = blockIdx.x*256 + threadIdx.x;
  if (g >= 512*64) return;
  int c = g >> 6, o = g & 63;
  float v = 0.0f;
  if (o < 18) v = cls_w[o*512 + c];
  else if (o < 54) v = bbox_w[(o-18)*512 + c];
  wh[g] = v;
}

// ---------------- 3) 3x3 conv via f64 MFMA (implicit GEMM), bias+relu, f32 out ---
// block = 256 thr (4 waves); tile = 64 oc x (4 rows x 16 cols); wave w = oc quarter.
// Operand lane split (trusted): non-K index = lane&15, K index = lane>>4, for both
// operands. C/D layout is NOT assumed: it is calibrated at runtime with two probe
// MFMAs (exact powers of two), robust to any D permutation and operand-role swap.
__global__ __launch_bounds__(256, 3) void conv3x3_mfma(
    const float* __restrict__ in, const float* __restrict__ wt,
    const float* __restrict__ bias, float* __restrict__ xout)
{
  __shared__ __align__(16) double wL[4608];   // [ic8*9+tap][64 oc]
  __shared__ __align__(16) double iL[864];    // [ic8][ry 0..5][rx 0..17]
  const int tid  = threadIdx.x;
  const int wave = tid >> 6, lane = tid & 63;
  const int kq = lane >> 4;        // K-group index
  const int ln = lane & 15;        // non-K index (oc for A-side, x for B-side)
  const int sp = blockIdx.x;       // 65 = 13 row-tiles x 5 col-tiles
  const int rt = sp / 5, ct = sp - rt*5;
  const int y0 = rt*4, x0 = ct*16;
  const int ocb = blockIdx.y;      // 0..7
  const int b = blockIdx.z;
  const float* inb = in + (size_t)b*1024*HWPIX;

  // ---- runtime C/D layout calibration ----
  int orow[4], ocol[4];
  {
    double pa  = (double)(1 << ln);                 // 2^(l&15), exact
    double msk = (kq == 0) ? 1.0 : 0.0;             // select K-group 0
    double4v z; z[0]=0.0; z[1]=0.0; z[2]=0.0; z[3]=0.0;
    double4v d1 = __builtin_amdgcn_mfma_f64_16x16x4f64(pa,  msk, z, 0, 0, 0);
    double4v d2 = __builtin_amdgcn_mfma_f64_16x16x4f64(msk, pa,  z, 0, 0, 0);
    #pragma unroll
    for (int e = 0; e < 4; ++e){
      orow[e] = (int)(((__double_as_longlong(d1[e]) >> 52) & 0x7FF) - 1023); // oc offset 0..15
      ocol[e] = (int)(((__double_as_longlong(d2[e]) >> 52) & 0x7FF) - 1023); // x  offset 0..15
    }
  }

  double4v acc[4];
  #pragma unroll
  for (int r = 0; r < 4; ++r){ acc[r][0]=0.0; acc[r][1]=0.0; acc[r][2]=0.0; acc[r][3]=0.0; }

  float wr[18], irg[4];

  auto load_chunk = [&](int icb){
    #pragma unroll
    for (int s = 0; s < 18; ++s){            // 18*256 == 4608 exactly
      int m = tid + s*256;
      int row = m >> 6, oc = m & 63;
      wr[s] = wt[(size_t)(icb*9 + row)*512 + ocb*64 + oc];
    }
    #pragma unroll
    for (int s = 0; s < 4; ++s){
      int m = tid + s*256;
      if (m < 864){
        int ic = m/108; int rem = m - ic*108;
        int ry = rem/18; int rx = rem - ry*18;
        int y = y0 - 1 + ry; int x = x0 - 1 + rx;
        irg[s] = ((unsigned)y < (unsigned)HH && (unsigned)x < (unsigned)WW)
                   ? inb[(size_t)(icb+ic)*HWPIX + y*WW + x] : 0.0f;
      }
    }
  };
  auto store_chunk = [&](){
    #pragma unroll
    for (int s = 0; s < 18; ++s) wL[tid + s*256] = (double)wr[s];
    #pragma unroll
    for (int s = 0; s < 4; ++s){
      int m = tid + s*256;
      if (m < 864) iL[m] = (double)irg[s];
    }
  };

  load_chunk(0);
  store_chunk();
  __syncthreads();

  #pragma unroll 1
  for (int icb = 0; icb < 1024; icb += 8){
    const bool more = (icb + 8) < 1024;
    if (more) load_chunk(icb + 8);
    #pragma unroll
    for (int h = 0; h < 2; ++h){
      #pragma unroll
      for (int tap = 0; tap < 9; ++tap){
        const int ky = tap/3, kx = tap - ky*3;
        double a = wL[((h*4 + kq)*9 + tap)*64 + wave*16 + ln];
        #pragma unroll
        for (int rr = 0; rr < 4; ++rr){
          double bb = iL[(h*4 + kq)*108 + (rr+ky)*18 + ln + kx];
          acc[rr] = __builtin_amdgcn_mfma_f64_16x16x4f64(a, bb, acc[rr], 0, 0, 0);
        }
      }
    }
    __syncthreads();
    if (more) store_chunk();
    __syncthreads();
  }

  #pragma unroll
  for (int rr = 0; rr < 4; ++rr){
    const int y = y0 + rr;
    if (y < HH){
      #pragma unroll
      for (int e = 0; e < 4; ++e){
        const int oc = ocb*64 + wave*16 + orow[e];
        const int xx = x0 + ocol[e];
        if (xx < WW){
          double val = acc[rr][e] + (double)bias[oc];
          val = fmax(val, 0.0);
          xout[((size_t)b*512 + oc)*HWPIX + y*WW + xx] = (float)val;
        }
      }
    }
  }
}

// ---------------- 4) 1x1 heads: hout[b][o<64][p<3840] = sum_c x[b][c][p]*wh[c][o]
__global__ __launch_bounds__(256) void head_mm(const float* __restrict__ x,
    const float* __restrict__ wh, double* __restrict__ hout)
{
  __shared__ float xs[32*128];
  __shared__ float wls[32*64];
  const int tid = threadIdx.x;
  const int b = blockIdx.y;
  const int p0 = blockIdx.x*128;
  const int oct = tid >> 5;      // 8 o-octets
  const int pq = tid & 31;       // 32 pixel quads
  double acc[8][4];
  #pragma unroll
  for (int k=0;k<8;++k){
    #pragma unroll
    for (int j=0;j<4;++j) acc[k][j]=0.0;
  }
  const float* xb = x + (size_t)b*512*HWPIX;
  #pragma unroll 1
  for (int cb = 0; cb < 512; cb += 32){
    for (int m = tid; m < 4096; m += 256){
      int cc = m >> 7; int px = m & 127;
      int p = p0 + px;
      xs[m] = (p < HWPIX) ? xb[(size_t)(cb+cc)*HWPIX + p] : 0.0f;
    }
    for (int m = tid; m < 2048; m += 256)
      wls[m] = wh[(size_t)(cb + (m >> 6))*64 + (m & 63)];
    __syncthreads();
    #pragma unroll 1
    for (int cc = 0; cc < 32; ++cc){
      const float4 xv = *(const float4*)&xs[cc*128 + pq*4];
      double xd0 = (double)xv.x, xd1 = (double)xv.y, xd2 = (double)xv.z, xd3 = (double)xv.w;
      const float* wp = &wls[cc*64 + oct*8];
      #pragma unroll
      for (int k = 0; k < 8; ++k){
        double w = (double)wp[k];
        acc[k][0] = fma(w, xd0, acc[k][0]);
        acc[k][1] = fma(w, xd1, acc[k][1]);
        acc[k][2] = fma(w, xd2, acc[k][2]);
        acc[k][3] = fma(w, xd3, acc[k][3]);
      }
    }
    __syncthreads();
  }
  #pragma unroll
  for (int k = 0; k < 8; ++k){
    #pragma unroll
    for (int j = 0; j < 4; ++j)
      hout[((size_t)b*64 + oct*8 + k)*HPAD + p0 + pq*4 + j] = acc[k][j];
  }
}

// ---------------- 5) sigmoid + anchor decode + clip + min-size + sort keys -------
__global__ void decode_boxes(const double* __restrict__ hout, const float* __restrict__ im_info,
    const float* __restrict__ cls_b, const float* __restrict__ bbox_b,
    double* __restrict__ sc, double* __restrict__ bxs, ulonglong2* __restrict__ keys)
{
  int g = blockIdx.x*256 + threadIdx.x;
  int b = g >> 16;
  int n = g & 65535;
  if (b >= NBATCH) return;
  ulonglong2 kv;
  if (n < NPROP){
    int p = n / 9; int a = n - p*9;
    int yr = p / WW; int xc = p - yr*WW;
    const double* hb = hout + (size_t)b*64*HPAD;
    double l0 = hb[(size_t)a*HPAD + p] + (double)cls_b[a];
    double l1 = hb[(size_t)(9+a)*HPAD + p] + (double)cls_b[9+a];
    double score = 1.0/(1.0 + exp(l0 - l1));
    double d0 = hb[(size_t)(18+4*a+0)*HPAD+p] + (double)bbox_b[4*a+0];
    double d1 = hb[(size_t)(18+4*a+1)*HPAD+p] + (double)bbox_b[4*a+1];
    double d2 = hb[(size_t)(18+4*a+2)*HPAD+p] + (double)bbox_b[4*a+2];
    double d3 = hb[(size_t)(18+4*a+3)*HPAD+p] + (double)bbox_b[4*a+3];
    double sx = 16.0*xc, sy = 16.0*yr;
    double ax1 = d_AB[a][0]+sx, ay1 = d_AB[a][1]+sy;
    double ax2 = d_AB[a][2]+sx, ay2 = d_AB[a][3]+sy;
    double aw = ax2-ax1+1.0, ah = ay2-ay1+1.0;
    double axc = ax1+0.5*aw, ayc = ay1+0.5*ah;
    double cx = axc + d0*aw, cy = ayc + d1*ah;
    double pw = exp(d2)*aw, ph = exp(d3)*ah;
    double i0 = (double)im_info[b*3+0];
    double i1 = (double)im_info[b*3+1];
    double i2 = (double)im_info[b*3+2];
    double x1 = cx - 0.5*pw, y1 = cy - 0.5*ph;
    double x2 = cx + 0.5*pw, y2 = cy + 0.5*ph;
    x1 = fmin(fmax(x1, 0.0), i1-1.0);
    x2 = fmin(fmax(x2, 0.0), i1-1.0);
    y1 = fmin(fmax(y1, 0.0), i0-1.0);
    y2 = fmin(fmax(y2, 0.0), i0-1.0);
    double wsz = x2-x1+1.0, hsz = y2-y1+1.0;
    double ms = 16.0*i2;
    double s = (wsz >= ms && hsz >= ms) ? score : -INFINITY;
    sc[(size_t)b*NPROP + n] = s;
    double* bp = bxs + ((size_t)b*NPROP + n)*4;
    bp[0]=x1; bp[1]=y1; bp[2]=x2; bp[3]=y2;
    unsigned long long u = (unsigned long long)__double_as_longlong(s);
    unsigned long long mm = (u >> 63) ? ~u : (u | 0x8000000000000000ULL);
    kv.x = ~mm; kv.y = (unsigned long long)n;
  } else {
    kv.x = ~0ULL; kv.y = (unsigned long long)n;   // padding sorts last
  }
  keys[(size_t)b*NSORT + n] = kv;
}

// ---------------- 6) bitonic sort, multi-kernel (whole-GPU parallel) -------------
__device__ __forceinline__ bool kgt(const ulonglong2& a, const ulonglong2& b){
  return (a.x > b.x) || (a.x == b.x && a.y > b.y);
}
// 6a: sort each 2048-chunk through stages k=2..2048 (128 blocks)
__global__ __launch_bounds__(1024) void sort_local(ulonglong2* __restrict__ keys){
  const int c = blockIdx.x & 31;
  const int b = blockIdx.x >> 5;
  ulonglong2* base = keys + (size_t)b*NSORT + c*2048;
  __shared__ ulonglong2 L[2048];
  const int tid = threadIdx.x;
  L[tid] = base[tid]; L[tid+1024] = base[tid+1024];
  __syncthreads();
  for (int k = 2; k <= 2048; k <<= 1){
    for (int j = k>>1; j > 0; j >>= 1){
      int i = ((tid & ~(j-1)) << 1) | (tid & (j-1));
      int l = i | j;
      bool asc = (((c*2048 + i) & k) == 0);
      ulonglong2 A = L[i], Bv = L[l];
      if (kgt(A,Bv) == asc){ L[i] = Bv; L[l] = A; }
      __syncthreads();
    }
  }
  base[tid] = L[tid]; base[tid+1024] = L[tid+1024];
}
// 6b: one global compare-swap step (j>=2048), 512 blocks x 256
__global__ void sort_gstep(ulonglong2* __restrict__ keys, int k, int j){
  int gid = blockIdx.x*256 + threadIdx.x;
  int b = gid >> 15;
  int q = gid & 32767;
  ulonglong2* base = keys + (size_t)b*NSORT;
  int i = ((q & ~(j-1)) << 1) | (q & (j-1));
  int l = i | j;
  bool asc = ((i & k) == 0);
  ulonglong2 A = base[i], Bv = base[l];
  if (kgt(A,Bv) == asc){ base[i] = Bv; base[l] = A; }
}
// 6c: finish stage k with chunk-local steps j=1024..1 (128 blocks)
__global__ __launch_bounds__(1024) void sort_lmerge(ulonglong2* __restrict__ keys, int k){
  const int c = blockIdx.x & 31;
  const int b = blockIdx.x >> 5;
  ulonglong2* base = keys + (size_t)b*NSORT + c*2048;
  __shared__ ulonglong2 L[2048];
  const int tid = threadIdx.x;
  L[tid] = base[tid]; L[tid+1024] = base[tid+1024];
  __syncthreads();
  for (int j = 1024; j > 0; j >>= 1){
    int i = ((tid & ~(j-1)) << 1) | (tid & (j-1));
    int l = i | j;
    bool asc = (((c*2048 + i) & k) == 0);
    ulonglong2 A = L[i], Bv = L[l];
    if (kgt(A,Bv) == asc){ L[i] = Bv; L[l] = A; }
    __syncthreads();
  }
  base[tid] = L[tid]; base[tid+1024] = L[tid+1024];
}

// ---------------- 7) gather top-6000 ---------------------------------------------
__global__ void gather_top(const ulonglong2* __restrict__ keys, const double* __restrict__ sc,
    const double* __restrict__ bxs, double* __restrict__ tsc, double* __restrict__ tbx)
{
  int r = blockIdx.x*256 + threadIdx.x;
  int b = blockIdx.y;
  if (r >= PRE) return;
  int idx = (int)keys[(size_t)b*NSORT + r].y;
  tsc[(size_t)b*PRE + r] = sc[(size_t)b*NPROP + idx];
  const double* sp = bxs + ((size_t)b*NPROP + idx)*4;
  double* dp = tbx + ((size_t)b*PRE + r)*4;
  dp[0]=sp[0]; dp[1]=sp[1]; dp[2]=sp[2]; dp[3]=sp[3];
}

// ---------------- 8) greedy NMS (exact argmax-loop semantics), 1 block/image -----
__global__ __launch_bounds__(1024) void nms_kernel(const double* __restrict__ tsc,
    const double* __restrict__ tbx, float* __restrict__ out)
{
  const int b = blockIdx.x;
  const int tid = threadIdx.x;
  __shared__ double sm[PRE];
  __shared__ double rv[16];
  __shared__ int ri[16];
  __shared__ double bb[5];
  const double* scb = tsc + (size_t)b*PRE;
  const double* bkb = tbx + (size_t)b*PRE*4;
  double bx[6][4];
  #pragma unroll
  for (int t = 0; t < 6; ++t){
    int i = t*1024 + tid;
    if (i < PRE){
      sm[i] = scb[i];
      bx[t][0] = bkb[i*4+0];
      bx[t][1] = bkb[i*4+1];
      bx[t][2] = bkb[i*4+2];
      bx[t][3] = bkb[i*4+3];
    }
  }
  __syncthreads();
  for (int it = 0; it < POST; ++it){
    double bv = -INFINITY; int bi = 0x7FFFFFFF;
    #pragma unroll
    for (int t = 0; t < 6; ++t){
      int i = t*1024 + tid;
      if (i < PRE){
        double v = sm[i];
        if (v > bv || (v == bv && i < bi)){ bv = v; bi = i; }
      }
    }
    #pragma unroll
    for (int off = 32; off > 0; off >>= 1){
      double ov = __shfl_down(bv, off);
      int oi = __shfl_down(bi, off);
      if (ov > bv || (ov == bv && oi < bi)){ bv = ov; bi = oi; }
    }
    if ((tid & 63) == 0){ rv[tid>>6] = bv; ri[tid>>6] = bi; }
    __syncthreads();
    if (tid == 0){
      for (int w = 1; w < 16; ++w){
        if (rv[w] > bv || (rv[w] == bv && ri[w] < bi)){ bv = rv[w]; bi = ri[w]; }
      }
      double jx1 = bkb[bi*4+0], jy1 = bkb[bi*4+1], jx2 = bkb[bi*4+2], jy2 = bkb[bi*4+3];
      bb[0]=jx1; bb[1]=jy1; bb[2]=jx2; bb[3]=jy2;
      bb[4] = (jx2-jx1+1.0)*(jy2-jy1+1.0);
      out[b*POST + it] = (float)scb[bi];
      float* ob = out + NBATCH*POST + (size_t)(b*POST + it)*4;
      ob[0]=(float)jx1; ob[1]=(float)jy1; ob[2]=(float)jx2; ob[3]=(float)jy2;
    }
    __syncthreads();
    double jx1 = bb[0], jy1 = bb[1], jx2 = bb[2], jy2 = bb[3], ja = bb[4];
    #pragma unroll
    for (int t = 0; t < 6; ++t){
      int i = t*1024 + tid;
      if (i < PRE){
        double xx1 = fmax(jx1, bx[t][0]);
        double yy1 = fmax(jy1, bx[t][1]);
        double xx2 = fmin(jx2, bx[t][2]);
        double yy2 = fmin(jy2, bx[t][3]);
        double iw = fmax(0.0, xx2-xx1+1.0);
        double ih = fmax(0.0, yy2-yy1+1.0);
        double inter = iw*ih;
        double ai = (bx[t][2]-bx[t][0]+1.0)*(bx[t][3]-bx[t][1]+1.0);
        double iou = inter/(ja + ai - inter);
        if (iou > 0.7) sm[i] = -INFINITY;
      }
    }
    __syncthreads();
  }
}

// =================================================================================
extern "C" void kernel_launch(void* const* d_in, const int* in_sizes, int n_in,
                              void* d_out, int out_size, void* d_ws, size_t ws_size,
                              hipStream_t stream) {
  (void)in_sizes; (void)n_in; (void)out_size; (void)ws_size;
  const float* base_feat = (const float*)d_in[0];
  const float* im_info   = (const float*)d_in[1];
  const float* conv_w = (const float*)d_in[4];
  const float* conv_b = (const float*)d_in[5];
  const float* cls_w  = (const float*)d_in[6];
  const float* cls_b  = (const float*)d_in[7];
  const float* bbox_w = (const float*)d_in[8];
  const float* bbox_b = (const float*)d_in[9];
  float* out = (float*)d_out;
  char* ws = (char*)d_ws;

  float*      w_t  = (float*)     (ws + 0);           // 9216*512 f32
  float*      xbuf = (float*)     (ws + 18874368);    // 4*512*3800 f32
  float*      wh   = (float*)     (ws + 50003968);    // 512*64 f32
  double*     hout = (double*)    (ws + 50135040);    // 4*64*3840 f64
  double*     scb  = (double*)    (ws + 57999360);    // 4*34200 f64
  double*     bxb  = (double*)    (ws + 59093760);    // 4*34200*4 f64
  ulonglong2* keys = (ulonglong2*)(ws + 63471360);    // 4*65536*16B
  double*     tops = (double*)    (ws + 67665664);    // 4*6000 f64
  double*     topb = (double*)    (ws + 67857664);    // 4*6000*4 f64

  transpose_w <<<dim3(288,16), dim3(32,8), 0, stream>>>(conv_w, w_t);
  prep_head_w <<<128, 256, 0, stream>>>(cls_w, bbox_w, wh);
  conv3x3_mfma<<<dim3(65,8,4), 256, 0, stream>>>(base_feat, w_t, conv_b, xbuf);
  head_mm     <<<dim3(30,4), 256, 0, stream>>>(xbuf, wh, hout);
  decode_boxes<<<1024, 256, 0, stream>>>(hout, im_info, cls_b, bbox_b, scb, bxb, keys);

  sort_local  <<<128, 1024, 0, stream>>>(keys);
  for (int k = 4096; k <= 65536; k <<= 1){
    for (int j = k>>1; j >= 2048; j >>= 1)
      sort_gstep<<<512, 256, 0, stream>>>(keys, k, j);
    sort_lmerge<<<128, 1024, 0, stream>>>(keys, k);
  }

  gather_top  <<<dim3(24,4), 256, 0, stream>>>(keys, scb, bxb, tops, topb);
  nms_kernel  <<<4, 1024, 0, stream>>>(tops, topb, out);
}

// Round 5
// 3342.175 us; speedup vs baseline: 3.0941x; 1.3307x over previous
//
#include <hip/hip_runtime.h>
#include <cstdint>
#include <math.h>

#define NBATCH 4
#define HH 50
#define WW 76
#define HWPIX 3800
#define HPAD 3840
#define NPROP 34200     // 50*76*9
#define NSORT 65536
#define PRE 6000
#define POST 300
#define NWORD 94        // ceil(6000/64)
#define NROWP 6016      // 94*64

typedef double double4v __attribute__((ext_vector_type(4)));

// py-faster-rcnn anchors, base 16, ratios {0.5,1,2}, scales {8,16,32} (exact integers)
__device__ __constant__ double d_AB[9][4] = {
  {-84.0,-40.0,99.0,55.0},
  {-176.0,-88.0,191.0,103.0},
  {-360.0,-184.0,375.0,199.0},
  {-56.0,-56.0,71.0,71.0},
  {-120.0,-120.0,135.0,135.0},
  {-248.0,-248.0,263.0,263.0},
  {-36.0,-80.0,51.0,95.0},
  {-80.0,-168.0,95.0,183.0},
  {-168.0,-344.0,183.0,359.0}
};

// ---------------- 1) transpose conv weights [512][9216] -> [9216][512] -----------
__global__ void transpose_w(const float* __restrict__ src, float* __restrict__ dst){
  __shared__ float t[32][33];
  const int kb = blockIdx.x*32, ob = blockIdx.y*32;
  const int lx = threadIdx.x, ly = threadIdx.y;   // 32 x 8
  #pragma unroll
  for (int m = 0; m < 32; m += 8){
    t[ly+m][lx] = src[(size_t)(ob+ly+m)*9216 + kb + lx];
  }
  __syncthreads();
  #pragma unroll
  for (int m = 0; m < 32; m += 8){
    dst[(size_t)(kb+ly+m)*512 + ob + lx] = t[lx][ly+m];
  }
}

// ---------------- 2) pack head weights into [c][64] (18 cls + 36 bbox + pad) -----
__global__ void prep_head_w(const float* __restrict__ cls_w, const float* __restrict__ bbox_w,
                            float* __restrict__ wh){
  int g = blockIdx.x*256 + threadIdx.x;
  if (g >= 512*64) return;
  int c = g >> 6, o = g & 63;
  float v = 0.0f;
  if (o < 18) v = cls_w[o*512 + c];
  else if (o < 54) v = bbox_w[(o-18)*512 + c];
  wh[g] = v;
}

// ---------------- 3) 3x3 conv via f64 MFMA, double-buffered LDS ------------------
// block = 256 thr (4 waves); tile = 64 oc x (5 rows x 16 cols); wave = oc quarter.
// K-chunk = 4 ic (K-group kq = lane>>4 maps to ic); dbuf -> 1 barrier/chunk,
// staging (regs->LDS of chunk c+1, global->regs of chunk c+2) overlaps compute.
// C/D layout calibrated at runtime with 2 probe MFMAs (verified working in R4).
__global__ __launch_bounds__(256, 3) void conv3x3_mfma(
    const float* __restrict__ in, const float* __restrict__ wt,
    const float* __restrict__ bias, float* __restrict__ xout)
{
  __shared__ __align__(16) double wA[2][2304];  // [buf][(ic4*9+tap)*64 + oc]
  __shared__ __align__(16) double iA[2][504];   // [buf][ic4*126 + ry*18 + rx]
  const int tid  = threadIdx.x;
  const int wave = tid >> 6, lane = tid & 63;
  const int kq = lane >> 4;        // K-group (ic within chunk)
  const int ln = lane & 15;        // non-K index (oc for A, x for B)
  const int sp = blockIdx.x;       // 50 = 10 row-tiles x 5 col-tiles
  const int rt = sp / 5, ct = sp - rt*5;
  const int y0 = rt*5, x0 = ct*16;
  const int ocb = blockIdx.y;      // 0..7
  const int b = blockIdx.z;
  const float* inb = in + (size_t)b*1024*HWPIX;

  // ---- runtime C/D layout calibration ----
  int orow[4], ocol[4];
  {
    double pa  = (double)(1 << ln);
    double msk = (kq == 0) ? 1.0 : 0.0;
    double4v z = {0.0, 0.0, 0.0, 0.0};
    double4v d1 = __builtin_amdgcn_mfma_f64_16x16x4f64(pa,  msk, z, 0, 0, 0);
    double4v d2 = __builtin_amdgcn_mfma_f64_16x16x4f64(msk, pa,  z, 0, 0, 0);
    #pragma unroll
    for (int e = 0; e < 4; ++e){
      orow[e] = (int)(((__double_as_longlong(d1[e]) >> 52) & 0x7FF) - 1023);
      ocol[e] = (int)(((__double_as_longlong(d2[e]) >> 52) & 0x7FF) - 1023);
    }
  }

  double4v acc[5];
  #pragma unroll
  for (int r = 0; r < 5; ++r){ acc[r][0]=0.0; acc[r][1]=0.0; acc[r][2]=0.0; acc[r][3]=0.0; }

  float wr[9], ir[2];

  auto load_chunk = [&](int icb){      // icb = first ic of chunk (multiple of 4)
    #pragma unroll
    for (int s = 0; s < 9; ++s){       // 9*256 == 2304 exactly
      int m = tid + s*256;
      int row = m >> 6, oc = m & 63;   // row = ic*9+tap (0..35)
      wr[s] = wt[(size_t)(icb*9 + row)*512 + ocb*64 + oc];
    }
    #pragma unroll
    for (int s = 0; s < 2; ++s){
      int m = tid + s*256;
      if (m < 504){
        int ic = m/126; int rem = m - ic*126;
        int ry = rem/18; int rx = rem - ry*18;   // ry 0..6, rx 0..17
        int y = y0 - 1 + ry; int x = x0 - 1 + rx;
        ir[s] = ((unsigned)y < (unsigned)HH && (unsigned)x < (unsigned)WW)
                  ? inb[(size_t)(icb+ic)*HWPIX + y*WW + x] : 0.0f;
      }
    }
  };
  auto store_chunk = [&](int buf){
    #pragma unroll
    for (int s = 0; s < 9; ++s) wA[buf][tid + s*256] = (double)wr[s];
    #pragma unroll
    for (int s = 0; s < 2; ++s){
      int m = tid + s*256;
      if (m < 504) iA[buf][m] = (double)ir[s];
    }
  };

  load_chunk(0);
  store_chunk(0);
  load_chunk(4);
  __syncthreads();

  #pragma unroll 1
  for (int c = 0; c < 256; ++c){
    const int cur = c & 1;
    if (c + 1 < 256){
      store_chunk(1 - cur);                    // chunk c+1 (safe: c-1 readers done)
      if (c + 2 < 256) load_chunk((c + 2)*4);  // prefetch chunk c+2 into regs
    }
    #pragma unroll
    for (int tap = 0; tap < 9; ++tap){
      const int ky = tap/3, kx = tap - ky*3;
      double a = wA[cur][(kq*9 + tap)*64 + wave*16 + ln];
      #pragma unroll
      for (int rr = 0; rr < 5; ++rr){
        double bb = iA[cur][kq*126 + (rr+ky)*18 + ln + kx];
        acc[rr] = __builtin_amdgcn_mfma_f64_16x16x4f64(a, bb, acc[rr], 0, 0, 0);
      }
    }
    __syncthreads();
  }

  #pragma unroll
  for (int rr = 0; rr < 5; ++rr){
    const int y = y0 + rr;                     // rows exact: always < 50
    #pragma unroll
    for (int e = 0; e < 4; ++e){
      const int oc = ocb*64 + wave*16 + orow[e];
      const int xx = x0 + ocol[e];
      if (xx < WW){
        double val = fmax(acc[rr][e] + (double)bias[oc], 0.0);
        xout[((size_t)b*512 + oc)*HWPIX + y*WW + xx] = (float)val;
      }
    }
  }
}

// ---------------- 4) 1x1 heads: hout[b][o<64][p<3840] = sum_c x[b][c][p]*wh[c][o]
__global__ __launch_bounds__(256) void head_mm(const float* __restrict__ x,
    const float* __restrict__ wh, double* __restrict__ hout)
{
  __shared__ float xs[32*128];
  __shared__ float wls[32*64];
  const int tid = threadIdx.x;
  const int b = blockIdx.y;
  const int p0 = blockIdx.x*128;
  const int oct = tid >> 5;      // 8 o-octets
  const int pq = tid & 31;       // 32 pixel quads
  double acc[8][4];
  #pragma unroll
  for (int k=0;k<8;++k){
    #pragma unroll
    for (int j=0;j<4;++j) acc[k][j]=0.0;
  }
  const float* xb = x + (size_t)b*512*HWPIX;
  #pragma unroll 1
  for (int cb = 0; cb < 512; cb += 32){
    for (int m = tid; m < 4096; m += 256){
      int cc = m >> 7; int px = m & 127;
      int p = p0 + px;
      xs[m] = (p < HWPIX) ? xb[(size_t)(cb+cc)*HWPIX + p] : 0.0f;
    }
    for (int m = tid; m < 2048; m += 256)
      wls[m] = wh[(size_t)(cb + (m >> 6))*64 + (m & 63)];
    __syncthreads();
    #pragma unroll 1
    for (int cc = 0; cc < 32; ++cc){
      const float4 xv = *(const float4*)&xs[cc*128 + pq*4];
      double xd0 = (double)xv.x, xd1 = (double)xv.y, xd2 = (double)xv.z, xd3 = (double)xv.w;
      const float* wp = &wls[cc*64 + oct*8];
      #pragma unroll
      for (int k = 0; k < 8; ++k){
        double w = (double)wp[k];
        acc[k][0] = fma(w, xd0, acc[k][0]);
        acc[k][1] = fma(w, xd1, acc[k][1]);
        acc[k][2] = fma(w, xd2, acc[k][2]);
        acc[k][3] = fma(w, xd3, acc[k][3]);
      }
    }
    __syncthreads();
  }
  #pragma unroll
  for (int k = 0; k < 8; ++k){
    #pragma unroll
    for (int j = 0; j < 4; ++j)
      hout[((size_t)b*64 + oct*8 + k)*HPAD + p0 + pq*4 + j] = acc[k][j];
  }
}

// ---------------- 5) sigmoid + anchor decode + clip + min-size + sort keys -------
__global__ void decode_boxes(const double* __restrict__ hout, const float* __restrict__ im_info,
    const float* __restrict__ cls_b, const float* __restrict__ bbox_b,
    double* __restrict__ sc, double* __restrict__ bxs, ulonglong2* __restrict__ keys)
{
  int g = blockIdx.x*256 + threadIdx.x;
  int b = g >> 16;
  int n = g & 65535;
  if (b >= NBATCH) return;
  ulonglong2 kv;
  if (n < NPROP){
    int p = n / 9; int a = n - p*9;
    int yr = p / WW; int xc = p - yr*WW;
    const double* hb = hout + (size_t)b*64*HPAD;
    double l0 = hb[(size_t)a*HPAD + p] + (double)cls_b[a];
    double l1 = hb[(size_t)(9+a)*HPAD + p] + (double)cls_b[9+a];
    double score = 1.0/(1.0 + exp(l0 - l1));
    double d0 = hb[(size_t)(18+4*a+0)*HPAD+p] + (double)bbox_b[4*a+0];
    double d1 = hb[(size_t)(18+4*a+1)*HPAD+p] + (double)bbox_b[4*a+1];
    double d2 = hb[(size_t)(18+4*a+2)*HPAD+p] + (double)bbox_b[4*a+2];
    double d3 = hb[(size_t)(18+4*a+3)*HPAD+p] + (double)bbox_b[4*a+3];
    double sx = 16.0*xc, sy = 16.0*yr;
    double ax1 = d_AB[a][0]+sx, ay1 = d_AB[a][1]+sy;
    double ax2 = d_AB[a][2]+sx, ay2 = d_AB[a][3]+sy;
    double aw = ax2-ax1+1.0, ah = ay2-ay1+1.0;
    double axc = ax1+0.5*aw, ayc = ay1+0.5*ah;
    double cx = axc + d0*aw, cy = ayc + d1*ah;
    double pw = exp(d2)*aw, ph = exp(d3)*ah;
    double i0 = (double)im_info[b*3+0];
    double i1 = (double)im_info[b*3+1];
    double i2 = (double)im_info[b*3+2];
    double x1 = cx - 0.5*pw, y1 = cy - 0.5*ph;
    double x2 = cx + 0.5*pw, y2 = cy + 0.5*ph;
    x1 = fmin(fmax(x1, 0.0), i1-1.0);
    x2 = fmin(fmax(x2, 0.0), i1-1.0);
    y1 = fmin(fmax(y1, 0.0), i0-1.0);
    y2 = fmin(fmax(y2, 0.0), i0-1.0);
    double wsz = x2-x1+1.0, hsz = y2-y1+1.0;
    double ms = 16.0*i2;
    double s = (wsz >= ms && hsz >= ms) ? score : -INFINITY;
    sc[(size_t)b*NPROP + n] = s;
    double* bp = bxs + ((size_t)b*NPROP + n)*4;
    bp[0]=x1; bp[1]=y1; bp[2]=x2; bp[3]=y2;
    unsigned long long u = (unsigned long long)__double_as_longlong(s);
    unsigned long long mm = (u >> 63) ? ~u : (u | 0x8000000000000000ULL);
    kv.x = ~mm; kv.y = (unsigned long long)n;
  } else {
    kv.x = ~0ULL; kv.y = (unsigned long long)n;   // padding sorts last
  }
  keys[(size_t)b*NSORT + n] = kv;
}

// ---------------- 6) bitonic sort, multi-kernel (whole-GPU parallel) -------------
__device__ __forceinline__ bool kgt(const ulonglong2& a, const ulonglong2& b){
  return (a.x > b.x) || (a.x == b.x && a.y > b.y);
}
__global__ __launch_bounds__(1024) void sort_local(ulonglong2* __restrict__ keys){
  const int c = blockIdx.x & 31;
  const int b = blockIdx.x >> 5;
  ulonglong2* base = keys + (size_t)b*NSORT + c*2048;
  __shared__ ulonglong2 L[2048];
  const int tid = threadIdx.x;
  L[tid] = base[tid]; L[tid+1024] = base[tid+1024];
  __syncthreads();
  for (int k = 2; k <= 2048; k <<= 1){
    for (int j = k>>1; j > 0; j >>= 1){
      int i = ((tid & ~(j-1)) << 1) | (tid & (j-1));
      int l = i | j;
      bool asc = (((c*2048 + i) & k) == 0);
      ulonglong2 A = L[i], Bv = L[l];
      if (kgt(A,Bv) == asc){ L[i] = Bv; L[l] = A; }
      __syncthreads();
    }
  }
  base[tid] = L[tid]; base[tid+1024] = L[tid+1024];
}
__global__ void sort_gstep(ulonglong2* __restrict__ keys, int k, int j){
  int gid = blockIdx.x*256 + threadIdx.x;
  int b = gid >> 15;
  int q = gid & 32767;
  ulonglong2* base = keys + (size_t)b*NSORT;
  int i = ((q & ~(j-1)) << 1) | (q & (j-1));
  int l = i | j;
  bool asc = ((i & k) == 0);
  ulonglong2 A = base[i], Bv = base[l];
  if (kgt(A,Bv) == asc){ base[i] = Bv; base[l] = A; }
}
__global__ __launch_bounds__(1024) void sort_lmerge(ulonglong2* __restrict__ keys, int k){
  const int c = blockIdx.x & 31;
  const int b = blockIdx.x >> 5;
  ulonglong2* base = keys + (size_t)b*NSORT + c*2048;
  __shared__ ulonglong2 L[2048];
  const int tid = threadIdx.x;
  L[tid] = base[tid]; L[tid+1024] = base[tid+1024];
  __syncthreads();
  for (int j = 1024; j > 0; j >>= 1){
    int i = ((tid & ~(j-1)) << 1) | (tid & (j-1));
    int l = i | j;
    bool asc = (((c*2048 + i) & k) == 0);
    ulonglong2 A = L[i], Bv = L[l];
    if (kgt(A,Bv) == asc){ L[i] = Bv; L[l] = A; }
    __syncthreads();
  }
  base[tid] = L[tid]; base[tid+1024] = L[tid+1024];
}

// ---------------- 7) gather top-6000 ---------------------------------------------
__global__ void gather_top(const ulonglong2* __restrict__ keys, const double* __restrict__ sc,
    const double* __restrict__ bxs, double* __restrict__ tsc, double* __restrict__ tbx)
{
  int r = blockIdx.x*256 + threadIdx.x;
  int b = blockIdx.y;
  if (r >= PRE) return;
  int idx = (int)keys[(size_t)b*NSORT + r].y;
  tsc[(size_t)b*PRE + r] = sc[(size_t)b*NPROP + idx];
  const double* sp = bxs + ((size_t)b*NPROP + idx)*4;
  double* dp = tbx + ((size_t)b*PRE + r)*4;
  dp[0]=sp[0]; dp[1]=sp[1]; dp[2]=sp[2]; dp[3]=sp[3];
}

// ---------------- 8a) IoU suppression bit-matrix (whole-GPU parallel) ------------
// rows[b][i][w] bit jj set iff iou(box_i, box_{w*64+jj}) > 0.7, exact ref formula.
__global__ __launch_bounds__(64) void nms_iou_rows(const double* __restrict__ tbx,
    unsigned long long* __restrict__ rows)
{
  const int w = blockIdx.x, icx = blockIdx.y, b = blockIdx.z;
  const int i = icx*64 + threadIdx.x;
  const int ii = i < PRE ? i : PRE-1;
  const double* bp = tbx + ((size_t)b*PRE + ii)*4;
  const double x1 = bp[0], y1 = bp[1], x2 = bp[2], y2 = bp[3];
  const double ai = (x2-x1+1.0)*(y2-y1+1.0);
  const int j0 = w*64;
  const int jn = (PRE - j0) < 64 ? (PRE - j0) : 64;
  unsigned long long bits = 0;
  for (int jj = 0; jj < jn; ++jj){
    const double* qp = tbx + ((size_t)b*PRE + j0 + jj)*4;   // wave-uniform
    double qx1 = qp[0], qy1 = qp[1], qx2 = qp[2], qy2 = qp[3];
    double xx1 = fmax(x1, qx1), yy1 = fmax(y1, qy1);
    double xx2 = fmin(x2, qx2), yy2 = fmin(y2, qy2);
    double inter = fmax(0.0, xx2-xx1+1.0) * fmax(0.0, yy2-yy1+1.0);
    double aj = (qx2-qx1+1.0)*(qy2-qy1+1.0);
    double iou = inter / (ai + aj - inter);
    if (iou > 0.7) bits |= (1ULL << jj);
  }
  rows[((size_t)b*NROWP + i)*NWORD + w] = bits;
}

// ---------------- 8b) greedy walk: scores sorted desc => argmax = first clear bit
__global__ __launch_bounds__(128) void nms_walk(const unsigned long long* __restrict__ rows,
    const double* __restrict__ tsc, const double* __restrict__ tbx, float* __restrict__ out)
{
  const int b = blockIdx.x;
  const int tid = threadIdx.x;
  __shared__ unsigned long long W[NWORD];
  __shared__ int s_p;
  if (tid < NWORD) W[tid] = 0ULL;
  __syncthreads();
  int f = 0;               // next candidate bit position (tid0 only)
  bool exhausted = false;  // tid0 only
  for (int it = 0; it < POST; ++it){
    if (tid == 0){
      int p = 0;
      if (!exhausted){
        int w = f >> 6;
        bool found = false;
        while (w < NWORD){
          unsigned long long valid = (w == NWORD-1) ? ((1ULL << (PRE - 64*(NWORD-1))) - 1ULL) : ~0ULL;
          unsigned long long fr = ~W[w] & valid;
          if (w == (f >> 6)) fr &= (~0ULL << (f & 63));
          if (fr){ p = w*64 + __ffsll((unsigned long long)fr) - 1; found = true; break; }
          ++w;
        }
        if (!found){ exhausted = true; p = 0; }   // ref: argmax of all -inf = 0
        else f = p + 1;
      }
      s_p = p;
    }
    __syncthreads();
    const int p = s_p;
    if (tid == 4) out[b*POST + it] = (float)tsc[(size_t)b*PRE + p];
    if (tid < 4)  out[NBATCH*POST + (size_t)(b*POST + it)*4 + tid]
                    = (float)tbx[((size_t)b*PRE + p)*4 + tid];
    if (tid < NWORD) W[tid] |= rows[((size_t)b*NROWP + p)*NWORD + tid];
    __syncthreads();
  }
}

// =================================================================================
extern "C" void kernel_launch(void* const* d_in, const int* in_sizes, int n_in,
                              void* d_out, int out_size, void* d_ws, size_t ws_size,
                              hipStream_t stream) {
  (void)in_sizes; (void)n_in; (void)out_size; (void)ws_size;
  const float* base_feat = (const float*)d_in[0];
  const float* im_info   = (const float*)d_in[1];
  const float* conv_w = (const float*)d_in[4];
  const float* conv_b = (const float*)d_in[5];
  const float* cls_w  = (const float*)d_in[6];
  const float* cls_b  = (const float*)d_in[7];
  const float* bbox_w = (const float*)d_in[8];
  const float* bbox_b = (const float*)d_in[9];
  float* out = (float*)d_out;
  char* ws = (char*)d_ws;

  float*      w_t  = (float*)     (ws + 0);           // 9216*512 f32 (dead after conv)
  float*      xbuf = (float*)     (ws + 18874368);    // 4*512*3800 f32
  float*      wh   = (float*)     (ws + 50003968);    // 512*64 f32
  double*     hout = (double*)    (ws + 50135040);    // 4*64*3840 f64
  double*     scb  = (double*)    (ws + 57999360);    // 4*34200 f64
  double*     bxb  = (double*)    (ws + 59093760);    // 4*34200*4 f64
  ulonglong2* keys = (ulonglong2*)(ws + 63471360);    // 4*65536*16B
  double*     tops = (double*)    (ws + 67665664);    // 4*6000 f64
  double*     topb = (double*)    (ws + 67857664);    // 4*6000*4 f64
  // rows time-shares the w_t region (18.10 MB <= 18.87 MB; w_t dead by then)
  unsigned long long* rows = (unsigned long long*)(ws + 0);

  transpose_w <<<dim3(288,16), dim3(32,8), 0, stream>>>(conv_w, w_t);
  prep_head_w <<<128, 256, 0, stream>>>(cls_w, bbox_w, wh);
  conv3x3_mfma<<<dim3(50,8,4), 256, 0, stream>>>(base_feat, w_t, conv_b, xbuf);
  head_mm     <<<dim3(30,4), 256, 0, stream>>>(xbuf, wh, hout);
  decode_boxes<<<1024, 256, 0, stream>>>(hout, im_info, cls_b, bbox_b, scb, bxb, keys);

  sort_local  <<<128, 1024, 0, stream>>>(keys);
  for (int k = 4096; k <= 65536; k <<= 1){
    for (int j = k>>1; j >= 2048; j >>= 1)
      sort_gstep<<<512, 256, 0, stream>>>(keys, k, j);
    sort_lmerge<<<128, 1024, 0, stream>>>(keys, k);
  }

  gather_top  <<<dim3(24,4), 256, 0, stream>>>(keys, scb, bxb, tops, topb);
  nms_iou_rows<<<dim3(NWORD,NWORD,NBATCH), 64, 0, stream>>>(topb, rows);
  nms_walk    <<<NBATCH, 128, 0, stream>>>(rows, tops, topb, out);
}

// Round 6
// 3122.363 us; speedup vs baseline: 3.3119x; 1.0704x over previous
//
#include <hip/hip_runtime.h>
#include <cstdint>
#include <math.h>

#define NBATCH 4
#define HH 50
#define WW 76
#define HWPIX 3800
#define HPAD 3840
#define NPROP 34200     // 50*76*9
#define NSORT 65536
#define PRE 6000
#define POST 300
#define NWORD 94        // ceil(6000/64)
#define NROWP 6016      // 94*64

typedef double double4v __attribute__((ext_vector_type(4)));

// py-faster-rcnn anchors, base 16, ratios {0.5,1,2}, scales {8,16,32} (exact integers)
__device__ __constant__ double d_AB[9][4] = {
  {-84.0,-40.0,99.0,55.0},
  {-176.0,-88.0,191.0,103.0},
  {-360.0,-184.0,375.0,199.0},
  {-56.0,-56.0,71.0,71.0},
  {-120.0,-120.0,135.0,135.0},
  {-248.0,-248.0,263.0,263.0},
  {-36.0,-80.0,51.0,95.0},
  {-80.0,-168.0,95.0,183.0},
  {-168.0,-344.0,183.0,359.0}
};

// ---------------- 1) transpose conv weights [512][9216] -> [9216][512] -----------
__global__ void transpose_w(const float* __restrict__ src, float* __restrict__ dst){
  __shared__ float t[32][33];
  const int kb = blockIdx.x*32, ob = blockIdx.y*32;
  const int lx = threadIdx.x, ly = threadIdx.y;   // 32 x 8
  #pragma unroll
  for (int m = 0; m < 32; m += 8){
    t[ly+m][lx] = src[(size_t)(ob+ly+m)*9216 + kb + lx];
  }
  __syncthreads();
  #pragma unroll
  for (int m = 0; m < 32; m += 8){
    dst[(size_t)(kb+ly+m)*512 + ob + lx] = t[lx][ly+m];
  }
}

// ---------------- 2) pack head weights into [c][64] (18 cls + 36 bbox + pad) -----
__global__ void prep_head_w(const float* __restrict__ cls_w, const float* __restrict__ bbox_w,
                            float* __restrict__ wh){
  int g = blockIdx.x*256 + threadIdx.x;
  if (g >= 512*64) return;
  int c = g >> 6, o = g & 63;
  float v = 0.0f;
  if (o < 18) v = cls_w[o*512 + c];
  else if (o < 54) v = bbox_w[(o-18)*512 + c];
  wh[g] = v;
}

// ---------------- 3) 3x3 conv via f64 MFMA, batch-folded, double-buffered --------
// block = 256 thr (4 waves); tile = 64 oc x (2 rows x 16 cols) x ALL 4 images;
// weights in LDS shared across images -> 4x MFMA per staged wA. Grid = 125x8 =
// 1000 blocks at 2 blocks/CU (55.3 KB LDS) -> 1.95 dispatch rounds (vs 2.08/3).
// C/D layout calibrated at runtime with 2 probe MFMAs (verified R4/R5).
__global__ __launch_bounds__(256, 2) void conv3x3_mfma(
    const float* __restrict__ in, const float* __restrict__ wt,
    const float* __restrict__ bias, float* __restrict__ xout)
{
  __shared__ __align__(16) double wA[2][2304];  // [buf][(ic4*9+tap)*64 + oc]
  __shared__ __align__(16) double iA[2][1152];  // [buf][img*288 + ic4*72 + ry*18 + rx]
  const int tid  = threadIdx.x;
  const int wave = tid >> 6, lane = tid & 63;
  const int kq = lane >> 4;        // K-group (ic within chunk)
  const int ln = lane & 15;        // non-K index (oc for A, x for B)
  const int sp = blockIdx.x;       // 125 = 25 row-tiles x 5 col-tiles
  const int rt = sp / 5, ct = sp - rt*5;
  const int y0 = rt*2, x0 = ct*16;
  const int ocb = blockIdx.y;      // 0..7

  // ---- runtime C/D layout calibration ----
  int orow[4], ocol[4];
  {
    double pa  = (double)(1 << ln);
    double msk = (kq == 0) ? 1.0 : 0.0;
    double4v z = {0.0, 0.0, 0.0, 0.0};
    double4v d1 = __builtin_amdgcn_mfma_f64_16x16x4f64(pa,  msk, z, 0, 0, 0);
    double4v d2 = __builtin_amdgcn_mfma_f64_16x16x4f64(msk, pa,  z, 0, 0, 0);
    #pragma unroll
    for (int e = 0; e < 4; ++e){
      orow[e] = (int)(((__double_as_longlong(d1[e]) >> 52) & 0x7FF) - 1023);
      ocol[e] = (int)(((__double_as_longlong(d2[e]) >> 52) & 0x7FF) - 1023);
    }
  }

  double4v acc[4][2];   // [img][row]
  #pragma unroll
  for (int g = 0; g < 4; ++g){
    #pragma unroll
    for (int r = 0; r < 2; ++r){ acc[g][r][0]=0.0; acc[g][r][1]=0.0; acc[g][r][2]=0.0; acc[g][r][3]=0.0; }
  }

  float wr[9], ir[5];

  auto load_chunk = [&](int icb){      // icb = first ic of chunk (multiple of 4)
    #pragma unroll
    for (int s = 0; s < 9; ++s){       // 9*256 == 2304 exactly
      int m = tid + s*256;
      int row = m >> 6, oc = m & 63;   // row = ic*9+tap (0..35)
      wr[s] = wt[(size_t)(icb*9 + row)*512 + ocb*64 + oc];
    }
    #pragma unroll
    for (int s = 0; s < 5; ++s){
      int m = tid + s*256;
      if (m < 1152){
        int img = m/288; int rem = m - img*288;
        int ic = rem/72; int r2 = rem - ic*72;
        int ry = r2/18; int rx = r2 - ry*18;     // ry 0..3, rx 0..17
        int y = y0 - 1 + ry; int x = x0 - 1 + rx;
        ir[s] = ((unsigned)y < (unsigned)HH && (unsigned)x < (unsigned)WW)
                  ? in[((size_t)img*1024 + icb + ic)*HWPIX + y*WW + x] : 0.0f;
      }
    }
  };
  auto store_chunk = [&](int buf){
    #pragma unroll
    for (int s = 0; s < 9; ++s) wA[buf][tid + s*256] = (double)wr[s];
    #pragma unroll
    for (int s = 0; s < 5; ++s){
      int m = tid + s*256;
      if (m < 1152) iA[buf][m] = (double)ir[s];
    }
  };

  load_chunk(0);
  store_chunk(0);
  load_chunk(4);
  __syncthreads();

  #pragma unroll 1
  for (int c = 0; c < 256; ++c){
    const int cur = c & 1;
    if (c + 1 < 256){
      store_chunk(1 - cur);                    // chunk c+1 (safe: c-1 readers done)
      if (c + 2 < 256) load_chunk((c + 2)*4);  // prefetch chunk c+2 into regs
    }
    #pragma unroll
    for (int tap = 0; tap < 9; ++tap){
      const int ky = tap/3, kx = tap - ky*3;
      double a = wA[cur][(kq*9 + tap)*64 + wave*16 + ln];
      #pragma unroll
      for (int img = 0; img < 4; ++img){
        #pragma unroll
        for (int rr = 0; rr < 2; ++rr){
          double bb = iA[cur][img*288 + kq*72 + (rr+ky)*18 + ln + kx];
          acc[img][rr] = __builtin_amdgcn_mfma_f64_16x16x4f64(a, bb, acc[img][rr], 0, 0, 0);
        }
      }
    }
    __syncthreads();
  }

  #pragma unroll
  for (int img = 0; img < 4; ++img){
    #pragma unroll
    for (int rr = 0; rr < 2; ++rr){
      const int y = y0 + rr;                   // rows exact: always < 50
      #pragma unroll
      for (int e = 0; e < 4; ++e){
        const int oc = ocb*64 + wave*16 + orow[e];
        const int xx = x0 + ocol[e];
        if (xx < WW){
          double val = fmax(acc[img][rr][e] + (double)bias[oc], 0.0);
          xout[((size_t)img*512 + oc)*HWPIX + y*WW + xx] = (float)val;
        }
      }
    }
  }
}

// ---------------- 4) 1x1 heads: hout[b][o<64][p<3840] = sum_c x[b][c][p]*wh[c][o]
__global__ __launch_bounds__(256) void head_mm(const float* __restrict__ x,
    const float* __restrict__ wh, double* __restrict__ hout)
{
  __shared__ float xs[32*128];
  __shared__ float wls[32*64];
  const int tid = threadIdx.x;
  const int b = blockIdx.y;
  const int p0 = blockIdx.x*128;
  const int oct = tid >> 5;      // 8 o-octets
  const int pq = tid & 31;       // 32 pixel quads
  double acc[8][4];
  #pragma unroll
  for (int k=0;k<8;++k){
    #pragma unroll
    for (int j=0;j<4;++j) acc[k][j]=0.0;
  }
  const float* xb = x + (size_t)b*512*HWPIX;
  #pragma unroll 1
  for (int cb = 0; cb < 512; cb += 32){
    for (int m = tid; m < 4096; m += 256){
      int cc = m >> 7; int px = m & 127;
      int p = p0 + px;
      xs[m] = (p < HWPIX) ? xb[(size_t)(cb+cc)*HWPIX + p] : 0.0f;
    }
    for (int m = tid; m < 2048; m += 256)
      wls[m] = wh[(size_t)(cb + (m >> 6))*64 + (m & 63)];
    __syncthreads();
    #pragma unroll 1
    for (int cc = 0; cc < 32; ++cc){
      const float4 xv = *(const float4*)&xs[cc*128 + pq*4];
      double xd0 = (double)xv.x, xd1 = (double)xv.y, xd2 = (double)xv.z, xd3 = (double)xv.w;
      const float* wp = &wls[cc*64 + oct*8];
      #pragma unroll
      for (int k = 0; k < 8; ++k){
        double w = (double)wp[k];
        acc[k][0] = fma(w, xd0, acc[k][0]);
        acc[k][1] = fma(w, xd1, acc[k][1]);
        acc[k][2] = fma(w, xd2, acc[k][2]);
        acc[k][3] = fma(w, xd3, acc[k][3]);
      }
    }
    __syncthreads();
  }
  #pragma unroll
  for (int k = 0; k < 8; ++k){
    #pragma unroll
    for (int j = 0; j < 4; ++j)
      hout[((size_t)b*64 + oct*8 + k)*HPAD + p0 + pq*4 + j] = acc[k][j];
  }
}

// ---------------- 5) sigmoid + anchor decode + clip + min-size + sort keys -------
__global__ void decode_boxes(const double* __restrict__ hout, const float* __restrict__ im_info,
    const float* __restrict__ cls_b, const float* __restrict__ bbox_b,
    double* __restrict__ sc, double* __restrict__ bxs, ulonglong2* __restrict__ keys)
{
  int g = blockIdx.x*256 + threadIdx.x;
  int b = g >> 16;
  int n = g & 65535;
  if (b >= NBATCH) return;
  ulonglong2 kv;
  if (n < NPROP){
    int p = n / 9; int a = n - p*9;
    int yr = p / WW; int xc = p - yr*WW;
    const double* hb = hout + (size_t)b*64*HPAD;
    double l0 = hb[(size_t)a*HPAD + p] + (double)cls_b[a];
    double l1 = hb[(size_t)(9+a)*HPAD + p] + (double)cls_b[9+a];
    double score = 1.0/(1.0 + exp(l0 - l1));
    double d0 = hb[(size_t)(18+4*a+0)*HPAD+p] + (double)bbox_b[4*a+0];
    double d1 = hb[(size_t)(18+4*a+1)*HPAD+p] + (double)bbox_b[4*a+1];
    double d2 = hb[(size_t)(18+4*a+2)*HPAD+p] + (double)bbox_b[4*a+2];
    double d3 = hb[(size_t)(18+4*a+3)*HPAD+p] + (double)bbox_b[4*a+3];
    double sx = 16.0*xc, sy = 16.0*yr;
    double ax1 = d_AB[a][0]+sx, ay1 = d_AB[a][1]+sy;
    double ax2 = d_AB[a][2]+sx, ay2 = d_AB[a][3]+sy;
    double aw = ax2-ax1+1.0, ah = ay2-ay1+1.0;
    double axc = ax1+0.5*aw, ayc = ay1+0.5*ah;
    double cx = axc + d0*aw, cy = ayc + d1*ah;
    double pw = exp(d2)*aw, ph = exp(d3)*ah;
    double i0 = (double)im_info[b*3+0];
    double i1 = (double)im_info[b*3+1];
    double i2 = (double)im_info[b*3+2];
    double x1 = cx - 0.5*pw, y1 = cy - 0.5*ph;
    double x2 = cx + 0.5*pw, y2 = cy + 0.5*ph;
    x1 = fmin(fmax(x1, 0.0), i1-1.0);
    x2 = fmin(fmax(x2, 0.0), i1-1.0);
    y1 = fmin(fmax(y1, 0.0), i0-1.0);
    y2 = fmin(fmax(y2, 0.0), i0-1.0);
    double wsz = x2-x1+1.0, hsz = y2-y1+1.0;
    double ms = 16.0*i2;
    double s = (wsz >= ms && hsz >= ms) ? score : -INFINITY;
    sc[(size_t)b*NPROP + n] = s;
    double* bp = bxs + ((size_t)b*NPROP + n)*4;
    bp[0]=x1; bp[1]=y1; bp[2]=x2; bp[3]=y2;
    unsigned long long u = (unsigned long long)__double_as_longlong(s);
    unsigned long long mm = (u >> 63) ? ~u : (u | 0x8000000000000000ULL);
    kv.x = ~mm; kv.y = (unsigned long long)n;
  } else {
    kv.x = ~0ULL; kv.y = (unsigned long long)n;   // padding sorts last
  }
  keys[(size_t)b*NSORT + n] = kv;
}

// ---------------- 6) bitonic sort, multi-kernel (whole-GPU parallel) -------------
__device__ __forceinline__ bool kgt(const ulonglong2& a, const ulonglong2& b){
  return (a.x > b.x) || (a.x == b.x && a.y > b.y);
}
__global__ __launch_bounds__(1024) void sort_local(ulonglong2* __restrict__ keys){
  const int c = blockIdx.x & 31;
  const int b = blockIdx.x >> 5;
  ulonglong2* base = keys + (size_t)b*NSORT + c*2048;
  __shared__ ulonglong2 L[2048];
  const int tid = threadIdx.x;
  L[tid] = base[tid]; L[tid+1024] = base[tid+1024];
  __syncthreads();
  for (int k = 2; k <= 2048; k <<= 1){
    for (int j = k>>1; j > 0; j >>= 1){
      int i = ((tid & ~(j-1)) << 1) | (tid & (j-1));
      int l = i | j;
      bool asc = (((c*2048 + i) & k) == 0);
      ulonglong2 A = L[i], Bv = L[l];
      if (kgt(A,Bv) == asc){ L[i] = Bv; L[l] = A; }
      __syncthreads();
    }
  }
  base[tid] = L[tid]; base[tid+1024] = L[tid+1024];
}
// single global step j>=2048
__global__ void sort_gstep(ulonglong2* __restrict__ keys, int k, int j){
  int gid = blockIdx.x*256 + threadIdx.x;
  int b = gid >> 15;
  int q = gid & 32767;
  ulonglong2* base = keys + (size_t)b*NSORT;
  int i = ((q & ~(j-1)) << 1) | (q & (j-1));
  int l = i | j;
  bool asc = ((i & k) == 0);
  ulonglong2 A = base[i], Bv = base[l];
  if (kgt(A,Bv) == asc){ base[i] = Bv; base[l] = A; }
}
// fused two steps j=2h,h on 4-tuples (k > 3h span -> asc uniform per tuple)
__global__ void sort_gstep2(ulonglong2* __restrict__ keys, int k, int h, int s){
  int gid = blockIdx.x*256 + threadIdx.x;   // 4 img x 16384 tuples
  int b = gid >> 14;
  int q = gid & 16383;
  ulonglong2* base = keys + (size_t)b*NSORT;
  int i0 = ((q >> s) << (s+2)) | (q & (h-1));
  bool asc = ((i0 & k) == 0);
  ulonglong2 e0 = base[i0], e1 = base[i0+h], e2 = base[i0+2*h], e3 = base[i0+3*h];
  ulonglong2 t;
  if (kgt(e0,e2) == asc){ t=e0; e0=e2; e2=t; }   // j=2h
  if (kgt(e1,e3) == asc){ t=e1; e1=e3; e3=t; }
  if (kgt(e0,e1) == asc){ t=e0; e0=e1; e1=t; }   // j=h
  if (kgt(e2,e3) == asc){ t=e2; e2=e3; e3=t; }
  base[i0]=e0; base[i0+h]=e1; base[i0+2*h]=e2; base[i0+3*h]=e3;
}
// fused three steps j=4h,2h,h on 8-tuples (k > 7h span -> asc uniform per tuple)
__global__ void sort_gstep3(ulonglong2* __restrict__ keys, int k, int h, int s){
  int gid = blockIdx.x*256 + threadIdx.x;   // 4 img x 8192 tuples
  int b = gid >> 13;
  int q = gid & 8191;
  ulonglong2* base = keys + (size_t)b*NSORT;
  int i0 = ((q >> s) << (s+3)) | (q & (h-1));
  bool asc = ((i0 & k) == 0);
  ulonglong2 e[8];
  #pragma unroll
  for (int t = 0; t < 8; ++t) e[t] = base[i0 + t*h];
  ulonglong2 t;
  #pragma unroll
  for (int a = 0; a < 4; ++a){                               // j=4h
    if (kgt(e[a],e[a+4]) == asc){ t=e[a]; e[a]=e[a+4]; e[a+4]=t; }
  }
  #pragma unroll
  for (int g = 0; g < 2; ++g){                               // j=2h
    #pragma unroll
    for (int a = 0; a < 2; ++a){
      int u = g*4 + a;
      if (kgt(e[u],e[u+2]) == asc){ t=e[u]; e[u]=e[u+2]; e[u+2]=t; }
    }
  }
  #pragma unroll
  for (int u = 0; u < 8; u += 2){                            // j=h
    if (kgt(e[u],e[u+1]) == asc){ t=e[u]; e[u]=e[u+1]; e[u+1]=t; }
  }
  #pragma unroll
  for (int t2 = 0; t2 < 8; ++t2) base[i0 + t2*h] = e[t2];
}
__global__ __launch_bounds__(1024) void sort_lmerge(ulonglong2* __restrict__ keys, int k){
  const int c = blockIdx.x & 31;
  const int b = blockIdx.x >> 5;
  ulonglong2* base = keys + (size_t)b*NSORT + c*2048;
  __shared__ ulonglong2 L[2048];
  const int tid = threadIdx.x;
  L[tid] = base[tid]; L[tid+1024] = base[tid+1024];
  __syncthreads();
  for (int j = 1024; j > 0; j >>= 1){
    int i = ((tid & ~(j-1)) << 1) | (tid & (j-1));
    int l = i | j;
    bool asc = (((c*2048 + i) & k) == 0);
    ulonglong2 A = L[i], Bv = L[l];
    if (kgt(A,Bv) == asc){ L[i] = Bv; L[l] = A; }
    __syncthreads();
  }
  base[tid] = L[tid]; base[tid+1024] = L[tid+1024];
}

// ---------------- 7) gather top-6000 ---------------------------------------------
__global__ void gather_top(const ulonglong2* __restrict__ keys, const double* __restrict__ sc,
    const double* __restrict__ bxs, double* __restrict__ tsc, double* __restrict__ tbx)
{
  int r = blockIdx.x*256 + threadIdx.x;
  int b = blockIdx.y;
  if (r >= PRE) return;
  int idx = (int)keys[(size_t)b*NSORT + r].y;
  tsc[(size_t)b*PRE + r] = sc[(size_t)b*NPROP + idx];
  const double* sp = bxs + ((size_t)b*NPROP + idx)*4;
  double* dp = tbx + ((size_t)b*PRE + r)*4;
  dp[0]=sp[0]; dp[1]=sp[1]; dp[2]=sp[2]; dp[3]=sp[3];
}

// ---------------- 8a) IoU suppression bit-matrix (whole-GPU parallel) ------------
__global__ __launch_bounds__(64) void nms_iou_rows(const double* __restrict__ tbx,
    unsigned long long* __restrict__ rows)
{
  const int w = blockIdx.x, icx = blockIdx.y, b = blockIdx.z;
  const int i = icx*64 + threadIdx.x;
  const int ii = i < PRE ? i : PRE-1;
  const double* bp = tbx + ((size_t)b*PRE + ii)*4;
  const double x1 = bp[0], y1 = bp[1], x2 = bp[2], y2 = bp[3];
  const double ai = (x2-x1+1.0)*(y2-y1+1.0);
  const int j0 = w*64;
  const int jn = (PRE - j0) < 64 ? (PRE - j0) : 64;
  unsigned long long bits = 0;
  for (int jj = 0; jj < jn; ++jj){
    const double* qp = tbx + ((size_t)b*PRE + j0 + jj)*4;   // wave-uniform
    double qx1 = qp[0], qy1 = qp[1], qx2 = qp[2], qy2 = qp[3];
    double xx1 = fmax(x1, qx1), yy1 = fmax(y1, qy1);
    double xx2 = fmin(x2, qx2), yy2 = fmin(y2, qy2);
    double inter = fmax(0.0, xx2-xx1+1.0) * fmax(0.0, yy2-yy1+1.0);
    double aj = (qx2-qx1+1.0)*(qy2-qy1+1.0);
    double iou = inter / (ai + aj - inter);
    if (iou > 0.7) bits |= (1ULL << jj);
  }
  rows[((size_t)b*NROWP + i)*NWORD + w] = bits;
}

// ---------------- 8b) greedy walk: scores sorted desc => argmax = first clear bit
__global__ __launch_bounds__(128) void nms_walk(const unsigned long long* __restrict__ rows,
    const double* __restrict__ tsc, const double* __restrict__ tbx, float* __restrict__ out)
{
  const int b = blockIdx.x;
  const int tid = threadIdx.x;
  __shared__ unsigned long long W[NWORD];
  __shared__ int s_p;
  if (tid < NWORD) W[tid] = 0ULL;
  __syncthreads();
  int f = 0;               // next candidate bit position (tid0 only)
  bool exhausted = false;  // tid0 only
  for (int it = 0; it < POST; ++it){
    if (tid == 0){
      int p = 0;
      if (!exhausted){
        int w = f >> 6;
        bool found = false;
        while (w < NWORD){
          unsigned long long valid = (w == NWORD-1) ? ((1ULL << (PRE - 64*(NWORD-1))) - 1ULL) : ~0ULL;
          unsigned long long fr = ~W[w] & valid;
          if (w == (f >> 6)) fr &= (~0ULL << (f & 63));
          if (fr){ p = w*64 + __ffsll((unsigned long long)fr) - 1; found = true; break; }
          ++w;
        }
        if (!found){ exhausted = true; p = 0; }   // ref: argmax of all -inf = 0
        else f = p + 1;
      }
      s_p = p;
    }
    __syncthreads();
    const int p = s_p;
    if (tid == 4) out[b*POST + it] = (float)tsc[(size_t)b*PRE + p];
    if (tid < 4)  out[NBATCH*POST + (size_t)(b*POST + it)*4 + tid]
                    = (float)tbx[((size_t)b*PRE + p)*4 + tid];
    if (tid < NWORD) W[tid] |= rows[((size_t)b*NROWP + p)*NWORD + tid];
    __syncthreads();
  }
}

// =================================================================================
extern "C" void kernel_launch(void* const* d_in, const int* in_sizes, int n_in,
                              void* d_out, int out_size, void* d_ws, size_t ws_size,
                              hipStream_t stream) {
  (void)in_sizes; (void)n_in; (void)out_size; (void)ws_size;
  const float* base_feat = (const float*)d_in[0];
  const float* im_info   = (const float*)d_in[1];
  const float* conv_w = (const float*)d_in[4];
  const float* conv_b = (const float*)d_in[5];
  const float* cls_w  = (const float*)d_in[6];
  const float* cls_b  = (const float*)d_in[7];
  const float* bbox_w = (const float*)d_in[8];
  const float* bbox_b = (const float*)d_in[9];
  float* out = (float*)d_out;
  char* ws = (char*)d_ws;

  float*      w_t  = (float*)     (ws + 0);           // 9216*512 f32 (dead after conv)
  float*      xbuf = (float*)     (ws + 18874368);    // 4*512*3800 f32
  float*      wh   = (float*)     (ws + 50003968);    // 512*64 f32
  double*     hout = (double*)    (ws + 50135040);    // 4*64*3840 f64
  double*     scb  = (double*)    (ws + 57999360);    // 4*34200 f64
  double*     bxb  = (double*)    (ws + 59093760);    // 4*34200*4 f64
  ulonglong2* keys = (ulonglong2*)(ws + 63471360);    // 4*65536*16B
  double*     tops = (double*)    (ws + 67665664);    // 4*6000 f64
  double*     topb = (double*)    (ws + 67857664);    // 4*6000*4 f64
  // rows time-shares the w_t region (18.10 MB <= 18.87 MB; w_t dead by then)
  unsigned long long* rows = (unsigned long long*)(ws + 0);

  transpose_w <<<dim3(288,16), dim3(32,8), 0, stream>>>(conv_w, w_t);
  prep_head_w <<<128, 256, 0, stream>>>(cls_w, bbox_w, wh);
  conv3x3_mfma<<<dim3(125,8), 256, 0, stream>>>(base_feat, w_t, conv_b, xbuf);
  head_mm     <<<dim3(30,4), 256, 0, stream>>>(xbuf, wh, hout);
  decode_boxes<<<1024, 256, 0, stream>>>(hout, im_info, cls_b, bbox_b, scb, bxb, keys);

  sort_local  <<<128, 1024, 0, stream>>>(keys);
  // k=4096: j=2048
  sort_gstep  <<<512, 256, 0, stream>>>(keys, 4096, 2048);
  sort_lmerge <<<128, 1024, 0, stream>>>(keys, 4096);
  // k=8192: j=4096,2048
  sort_gstep2 <<<256, 256, 0, stream>>>(keys, 8192, 2048, 11);
  sort_lmerge <<<128, 1024, 0, stream>>>(keys, 8192);
  // k=16384: j=8192,4096,2048
  sort_gstep3 <<<128, 256, 0, stream>>>(keys, 16384, 2048, 11);
  sort_lmerge <<<128, 1024, 0, stream>>>(keys, 16384);
  // k=32768: j=16384,8192,4096 then 2048
  sort_gstep3 <<<128, 256, 0, stream>>>(keys, 32768, 4096, 12);
  sort_gstep  <<<512, 256, 0, stream>>>(keys, 32768, 2048);
  sort_lmerge <<<128, 1024, 0, stream>>>(keys, 32768);
  // k=65536: j=32768,16384,8192 then 4096,2048
  sort_gstep3 <<<128, 256, 0, stream>>>(keys, 65536, 8192, 13);
  sort_gstep2 <<<256, 256, 0, stream>>>(keys, 65536, 2048, 11);
  sort_lmerge <<<128, 1024, 0, stream>>>(keys, 65536);

  gather_top  <<<dim3(24,4), 256, 0, stream>>>(keys, scb, bxb, tops, topb);
  nms_iou_rows<<<dim3(NWORD,NWORD,NBATCH), 64, 0, stream>>>(topb, rows);
  nms_walk    <<<NBATCH, 128, 0, stream>>>(rows, tops, topb, out);
}